// Round 18
// baseline (150.504 us; speedup 1.0000x reference)
//
#include <hip/hip_runtime.h>

typedef __attribute__((ext_vector_type(8))) __bf16 bf16x8;
typedef __attribute__((ext_vector_type(8))) unsigned short u16x8;
typedef __attribute__((ext_vector_type(4))) unsigned short u16x4;
typedef __attribute__((ext_vector_type(4))) float f32x4;

#define NEGV (-1e30f)

// ---------------------------------------------------------------------------
// Workspace layout (bytes):
//  Bh  : [1152][1024] bf16  @ 0          (2,359,296)
//  Bl  : [1152][1024] bf16  @ 2359296    (2,359,296)
//  LR  : [48][8192]  f32    @ 21495808   (1,572,864)
//  Vt  : [8][16][128][512] bf16 @ 23068672 (16,777,216)  written by mgemm
//  adjB: [16][512][512] u8  @ 39845888   (4,194,304)
//  total 44,040,192 B
// ---------------------------------------------------------------------------

__device__ __forceinline__ unsigned short f2bf(float f) {
    unsigned int u = __float_as_uint(f);
    u += 0x7fffu + ((u >> 16) & 1u);
    return (unsigned short)(u >> 16);
}
__device__ __forceinline__ float b2f(unsigned short h) {
    return __uint_as_float(((unsigned int)h) << 16);
}
// RNE via hardware cvt (v_cvt_pk_bf16_f32); bitwise == f2bf on finite inputs.
__device__ __forceinline__ unsigned short f2bf_rn(float f) {
    union { __bf16 b; unsigned short u; } c;
    c.b = (__bf16)f;
    return c.u;
}

// ---------------------------------------------------------------------------
// Kernel 1: fused prep (adj->bytes + pack tr/wa/zero).  grid 1616:
//   bid <1024          : adj int32 -> adjB bytes (16B per thread)
//   1024<=bid<1152     : W_last columns via LDS transpose
//   1152<=bid<1536     : W.a columns via LDS-staged matvec
//   bid>=1536          : zero pad columns 1072..1151
// ---------------------------------------------------------------------------
__global__ __launch_bounds__(256) void prep_kernel(const int* __restrict__ adj,
                                                   const float* __restrict__ W,
                                                   const float* __restrict__ a1,
                                                   const float* __restrict__ a2,
                                                   unsigned short* __restrict__ Bh,
                                                   unsigned short* __restrict__ Bl,
                                                   unsigned char* __restrict__ adjB) {
    __shared__ float tile[64 * 133];
    const int bid = blockIdx.x;
    const int tid = threadIdx.x;

    if (bid < 1024) {
        const int idx = bid * 256 + tid;
        const int4* s = (const int4*)(adj + (size_t)idx * 16);
        int4 v0 = s[0], v1 = s[1], v2 = s[2], v3 = s[3];
        union { unsigned char c[16]; int4 v; } o;
        o.c[0] = (unsigned char)v0.x; o.c[1] = (unsigned char)v0.y;
        o.c[2] = (unsigned char)v0.z; o.c[3] = (unsigned char)v0.w;
        o.c[4] = (unsigned char)v1.x; o.c[5] = (unsigned char)v1.y;
        o.c[6] = (unsigned char)v1.z; o.c[7] = (unsigned char)v1.w;
        o.c[8] = (unsigned char)v2.x; o.c[9] = (unsigned char)v2.y;
        o.c[10] = (unsigned char)v2.z; o.c[11] = (unsigned char)v2.w;
        o.c[12] = (unsigned char)v3.x; o.c[13] = (unsigned char)v3.y;
        o.c[14] = (unsigned char)v3.z; o.c[15] = (unsigned char)v3.w;
        *(int4*)(adjB + (size_t)idx * 16) = o.v;
    } else if (bid < 1152) {
        const int pb = bid - 1024;
        const int kt = pb & 15, h = pb >> 4;
        const int k0 = kt * 64;
        const float* wsrc = W + ((size_t)((h * 3 + 2) * 1024) + k0) * 128;

        #pragma unroll
        for (int rep = 0; rep < 8; ++rep) {
            int idx = rep * 256 + tid;
            int k = idx >> 5, dc = (idx & 31) * 4;
            float4 v = *(const float4*)(wsrc + (size_t)k * 128 + dc);
            tile[k * 133 + dc + 0] = v.x;
            tile[k * 133 + dc + 1] = v.y;
            tile[k * 133 + dc + 2] = v.z;
            tile[k * 133 + dc + 3] = v.w;
        }
        __syncthreads();
        #pragma unroll
        for (int rep = 0; rep < 4; ++rep) {
            int idx = rep * 256 + tid;
            int d = idx >> 3, kc = (idx & 7) * 8;
            u16x8 vh, vl;
            #pragma unroll
            for (int q = 0; q < 8; ++q) {
                float f = tile[(kc + q) * 133 + d];
                unsigned short hi = f2bf(f);
                vh[q] = hi;
                vl[q] = f2bf(f - b2f(hi));
            }
            size_t o = (size_t)(h * 128 + d) * 1024 + k0 + kc;
            *(u16x8*)(Bh + o) = vh;
            *(u16x8*)(Bl + o) = vl;
        }
    } else if (bid < 1536) {
        const int pb = bid - 1152;
        const int kt = pb & 15, ht = pb >> 4;
        const int h = ht & 7, t = ht >> 3;
        const int k0 = kt * 64;
        const float* wsrc = W + ((size_t)((h * 3 + t) * 1024) + k0) * 128;

        #pragma unroll
        for (int rep = 0; rep < 8; ++rep) {
            int idx = rep * 256 + tid;
            int k = idx >> 5, dc = (idx & 31) * 4;
            float4 v = *(const float4*)(wsrc + (size_t)k * 128 + dc);
            tile[k * 133 + dc + 0] = v.x;
            tile[k * 133 + dc + 1] = v.y;
            tile[k * 133 + dc + 2] = v.z;
            tile[k * 133 + dc + 3] = v.w;
        }
        __syncthreads();
        if (tid < 128) {
            const int k = tid & 63, s = tid >> 6;
            const float* ar = (s ? a2 : a1) + (h * 3 + t) * 128;
            float acc = 0.f;
            #pragma unroll 4
            for (int d = 0; d < 128; ++d) acc += tile[k * 133 + d] * ar[d];
            unsigned short hi = f2bf(acc);
            size_t o = (size_t)(1024 + s * 24 + t * 8 + h) * 1024 + k0 + k;
            Bh[o] = hi;
            Bl[o] = f2bf(acc - b2f(hi));
        }
    } else {
        const int n = 1072 + (bid - 1536);
        *(unsigned long long*)(Bh + (size_t)n * 1024 + tid * 4) = 0ull;
        *(unsigned long long*)(Bl + (size_t)n * 1024 + tid * 4) = 0ull;
    }
}

// ---------------------------------------------------------------------------
// Kernel 2: bf16x3 MFMA GEMM — r17 structure with BK=64 two-half unroll:
//   two BK=32 substeps staged+computed per barrier pair (16 pairs vs 32).
//   LDS = 8 x [128][32] panels (64KB); per-half layout/staging/fragments are
//   BIT-IDENTICAL to the proven r10/r17 code — only barrier count halves.
// ---------------------------------------------------------------------------
__global__ __launch_bounds__(256, 2) void mgemm(const float* __restrict__ X,
                                                const unsigned short* __restrict__ Bh,
                                                const unsigned short* __restrict__ Bl,
                                                const float* __restrict__ nm,
                                                unsigned short* __restrict__ Vt,
                                                float* __restrict__ LR) {
    __shared__ unsigned short Ah[2][128 * 32];
    __shared__ unsigned short Al[2][128 * 32];
    __shared__ unsigned short Bhs[2][128 * 32];
    __shared__ unsigned short Bls[2][128 * 32];

    const int bid = blockIdx.x;                 // 0..575
    const int swz = (bid & 7) * 72 + (bid >> 3); // XCD-aware, bijective
    const int nt = swz % 9, mt = swz / 9;
    const int n0 = nt * 128, m0 = mt * 128;

    const int tid = threadIdx.x;
    const int lane = tid & 63, w = tid >> 6;
    const int wr = w >> 1, wc = w & 1;
    const int fr = lane & 15, fq = lane >> 4;

    f32x4 acc[4][4];
    #pragma unroll
    for (int m = 0; m < 4; ++m)
        #pragma unroll
        for (int n = 0; n < 4; ++n) acc[m][n] = (f32x4){0.f, 0.f, 0.f, 0.f};

    const int arow = tid >> 1, ahalf = tid & 1;
    const float* xs = X + (size_t)(m0 + arow) * 1024 + ahalf * 16;
    const int aoff = arow * 32 + ahalf * 16;

    for (int k0 = 0; k0 < 1024; k0 += 64) {
        __syncthreads();  // previous compute done before LDS overwrite

        // ---- stage B: both halves, same per-half mapping as r10
        #pragma unroll
        for (int hf = 0; hf < 2; ++hf) {
            #pragma unroll
            for (int q = 0; q < 2; ++q) {
                const int s = q * 256 + tid;
                const int brow = s >> 2, bkb = s & 3;
                const unsigned short* gh = Bh + (size_t)(n0 + brow) * 1024 + k0 + hf * 32 + bkb * 8;
                const unsigned short* gl = Bl + (size_t)(n0 + brow) * 1024 + k0 + hf * 32 + bkb * 8;
                unsigned short* dh = &Bhs[hf][(q * 256 + w * 64) * 8];
                unsigned short* dl = &Bls[hf][(q * 256 + w * 64) * 8];
                __builtin_amdgcn_global_load_lds(
                    (const __attribute__((address_space(1))) void*)gh,
                    (__attribute__((address_space(3))) void*)dh, 16, 0, 0);
                __builtin_amdgcn_global_load_lds(
                    (const __attribute__((address_space(1))) void*)gl,
                    (__attribute__((address_space(3))) void*)dl, 16, 0, 0);
            }
        }

        // ---- stage A: both halves (sequential to cap VGPR)
        #pragma unroll
        for (int hf = 0; hf < 2; ++hf) {
            float xf[16];
            #pragma unroll
            for (int i = 0; i < 4; ++i) {
                float4 v = *(const float4*)(xs + k0 + hf * 32 + i * 4);
                xf[i * 4 + 0] = v.x; xf[i * 4 + 1] = v.y;
                xf[i * 4 + 2] = v.z; xf[i * 4 + 3] = v.w;
            }
            u16x8 vh0, vh1, vl0, vl1;
            #pragma unroll
            for (int i = 0; i < 8; ++i) {
                unsigned short hi = f2bf_rn(xf[i]);
                vh0[i] = hi;
                vl0[i] = f2bf_rn(xf[i] - b2f(hi));
            }
            #pragma unroll
            for (int i = 0; i < 8; ++i) {
                unsigned short hi = f2bf_rn(xf[8 + i]);
                vh1[i] = hi;
                vl1[i] = f2bf_rn(xf[8 + i] - b2f(hi));
            }
            *(u16x8*)(&Ah[hf][aoff]) = vh0;
            *(u16x8*)(&Ah[hf][aoff + 8]) = vh1;
            *(u16x8*)(&Al[hf][aoff]) = vl0;
            *(u16x8*)(&Al[hf][aoff + 8]) = vl1;
        }

        __syncthreads();  // one drain for both halves

        // ---- compute: both halves, per-half code verbatim r17
        #pragma unroll
        for (int hf = 0; hf < 2; ++hf) {
            bf16x8 amh[4], bnh[4];
            #pragma unroll
            for (int m = 0; m < 4; ++m)
                amh[m] = *(bf16x8*)(&Ah[hf][(wr * 64 + m * 16 + fr) * 32 + fq * 8]);
            #pragma unroll
            for (int n = 0; n < 4; ++n)
                bnh[n] = *(bf16x8*)(&Bhs[hf][(wc * 64 + n * 16 + fr) * 32 + fq * 8]);
            #pragma unroll
            for (int m = 0; m < 4; ++m)
                #pragma unroll
                for (int n = 0; n < 4; ++n)
                    acc[m][n] = __builtin_amdgcn_mfma_f32_16x16x32_bf16(amh[m], bnh[n], acc[m][n], 0, 0, 0);

            bf16x8 bnl[4];
            #pragma unroll
            for (int n = 0; n < 4; ++n)
                bnl[n] = *(bf16x8*)(&Bls[hf][(wc * 64 + n * 16 + fr) * 32 + fq * 8]);
            #pragma unroll
            for (int m = 0; m < 4; ++m)
                #pragma unroll
                for (int n = 0; n < 4; ++n)
                    acc[m][n] = __builtin_amdgcn_mfma_f32_16x16x32_bf16(amh[m], bnl[n], acc[m][n], 0, 0, 0);

            bf16x8 aml[4];
            #pragma unroll
            for (int m = 0; m < 4; ++m)
                aml[m] = *(bf16x8*)(&Al[hf][(wr * 64 + m * 16 + fr) * 32 + fq * 8]);
            #pragma unroll
            for (int m = 0; m < 4; ++m)
                #pragma unroll
                for (int n = 0; n < 4; ++n)
                    acc[m][n] = __builtin_amdgcn_mfma_f32_16x16x32_bf16(aml[m], bnh[n], acc[m][n], 0, 0, 0);
        }
    }

    // ---- epilogue: C/D layout col=lane&15, row=(lane>>4)*4+reg
    if (nt < 8) {
        const int b_ = (mt * 128) >> 9;
        const int jb0 = (mt & 3) * 128;
        unsigned short* vtw = Vt + (size_t)(nt * 16 + b_) * 128 * 512;
        #pragma unroll
        for (int m = 0; m < 4; ++m) {
            const int jb = jb0 + wr * 64 + m * 16 + fq * 4;
            float mk[4];
            #pragma unroll
            for (int r = 0; r < 4; ++r)
                mk[r] = nm[m0 + wr * 64 + m * 16 + fq * 4 + r];
            #pragma unroll
            for (int n = 0; n < 4; ++n) {
                const int d = wc * 64 + n * 16 + fr;
                u16x4 pk;
                #pragma unroll
                for (int r = 0; r < 4; ++r) pk[r] = f2bf_rn(acc[m][n][r] * mk[r]);
                *(u16x4*)(vtw + (size_t)d * 512 + jb) = pk;
            }
        }
    } else {
        #pragma unroll
        for (int m = 0; m < 4; ++m) {
            #pragma unroll
            for (int r = 0; r < 4; ++r) {
                const int R = m0 + wr * 64 + m * 16 + fq * 4 + r;
                #pragma unroll
                for (int n = 0; n < 4; ++n) {
                    const int c = wc * 64 + n * 16 + fr;
                    if (c < 48) LR[(size_t)c * 8192 + R] = acc[m][n][r];
                }
            }
        }
    }
}

// ---------------------------------------------------------------------------
// Kernel 4: fused attn — r17-exact (verified)
// ---------------------------------------------------------------------------
__global__ __launch_bounds__(256, 4) void attn_kernel(const unsigned short* __restrict__ Vt,
                                                      const float* __restrict__ LR,
                                                      const unsigned char* __restrict__ adjB,
                                                      float* __restrict__ out) {
    __shared__ __align__(16) unsigned short Vb[2][16 * 512];
    __shared__ __align__(16) float rt[3 * 512];

    const int bid = blockIdx.x;
    const int itg = bid >> 7, hb = bid & 127, h = hb >> 4, b = hb & 15;
    const int tid = threadIdx.x, w = tid >> 6, lane = tid & 63;
    const int fr = lane & 15, fq = lane >> 4;
    const int i0 = (itg * 4 + w) * 16;
    const int fq8 = fq * 8;

    for (int idx = tid; idx < 1536; idx += 256) {
        int t = idx >> 9, j = idx & 511;
        rt[idx] = LR[(size_t)(24 + t * 8 + h) * 8192 + b * 512 + j];
    }
    const float lf0 = LR[(size_t)(h) * 8192 + b * 512 + i0 + fr];
    const float lf1 = LR[(size_t)(8 + h) * 8192 + b * 512 + i0 + fr];
    const float lf2 = LR[(size_t)(16 + h) * 8192 + b * 512 + i0 + fr];
    const unsigned char* arow = adjB + (size_t)(b * 512 + i0 + fr) * 512;
    const unsigned short* vt = Vt + (size_t)(h * 16 + b) * 128 * 512;

#define STAGE_V(bufp, os_) do {                                                   \
        _Pragma("unroll")                                                          \
        for (int q_ = 0; q_ < 4; ++q_) {                                           \
            const int nh_ = q_ * 4 + w;                                            \
            const unsigned short* src_ = vt + (size_t)((nh_ >> 1) * 16 + fr) * 512 \
                                          + (os_) * 64 + (nh_ & 1) * 32 + fq8;     \
            unsigned short* dst_ = (bufp) + nh_ * 512;                             \
            __builtin_amdgcn_global_load_lds(                                      \
                (const __attribute__((address_space(1))) void*)src_,               \
                (__attribute__((address_space(3))) void*)dst_, 16, 0, 0);          \
        }                                                                          \
    } while (0)

    STAGE_V(&Vb[0][0], 0);
    uint2 aA = *(const uint2*)(arow + fq8);
    uint2 aB = *(const uint2*)(arow + fq8 + 32);

    f32x4 acc[8];
    #pragma unroll
    for (int n = 0; n < 8; ++n) acc[n] = (f32x4){0.f, 0.f, 0.f, 0.f};
    float rsum = 0.f;

    __syncthreads();

    #pragma unroll 1
    for (int os = 0; os < 8; ++os) {
        unsigned short* vb = &Vb[os & 1][0];
        if (os < 7) STAGE_V(&Vb[(os & 1) ^ 1][0], os + 1);

        const int jA = os * 64 + fq8;
        const int jB = jA + 32;

        u16x8 vhA, vlA, vhB, vlB;
        {
            float4 r0a = *(const float4*)(rt + jA), r0b = *(const float4*)(rt + jA + 4);
            float4 r1a = *(const float4*)(rt + 512 + jA), r1b = *(const float4*)(rt + 512 + jA + 4);
            float4 r2a = *(const float4*)(rt + 1024 + jA), r2b = *(const float4*)(rt + 1024 + jA + 4);
            float e0[8] = {r0a.x, r0a.y, r0a.z, r0a.w, r0b.x, r0b.y, r0b.z, r0b.w};
            float e1[8] = {r1a.x, r1a.y, r1a.z, r1a.w, r1b.x, r1b.y, r1b.z, r1b.w};
            float e2[8] = {r2a.x, r2a.y, r2a.z, r2a.w, r2b.x, r2b.y, r2b.z, r2b.w};
            #pragma unroll
            for (int q = 0; q < 8; ++q) {
                unsigned av = ((q < 4 ? aA.x : aA.y) >> (8 * (q & 3))) & 255u;
                float sb = (av == 1u) ? (lf0 + e0[q])
                         : (av == 2u) ? (lf1 + e1[q]) : (lf2 + e2[q]);
                float sv = fmaxf(sb, 0.f) + 0.2f * fminf(sb, 0.f);
                float p = (av != 0u) ? __expf(sv) : 0.f;
                rsum += p;
                unsigned short hi = f2bf_rn(p);
                vhA[q] = hi;
                vlA[q] = f2bf_rn(p - b2f(hi));
            }
        }
        {
            float4 r0a = *(const float4*)(rt + jB), r0b = *(const float4*)(rt + jB + 4);
            float4 r1a = *(const float4*)(rt + 512 + jB), r1b = *(const float4*)(rt + 512 + jB + 4);
            float4 r2a = *(const float4*)(rt + 1024 + jB), r2b = *(const float4*)(rt + 1024 + jB + 4);
            float e0[8] = {r0a.x, r0a.y, r0a.z, r0a.w, r0b.x, r0b.y, r0b.z, r0b.w};
            float e1[8] = {r1a.x, r1a.y, r1a.z, r1a.w, r1b.x, r1b.y, r1b.z, r1b.w};
            float e2[8] = {r2a.x, r2a.y, r2a.z, r2a.w, r2b.x, r2b.y, r2b.z, r2b.w};
            #pragma unroll
            for (int q = 0; q < 8; ++q) {
                unsigned av = ((q < 4 ? aB.x : aB.y) >> (8 * (q & 3))) & 255u;
                float sb = (av == 1u) ? (lf0 + e0[q])
                         : (av == 2u) ? (lf1 + e1[q]) : (lf2 + e2[q]);
                float sv = fmaxf(sb, 0.f) + 0.2f * fminf(sb, 0.f);
                float p = (av != 0u) ? __expf(sv) : 0.f;
                rsum += p;
                unsigned short hi = f2bf_rn(p);
                vhB[q] = hi;
                vlB[q] = f2bf_rn(p - b2f(hi));
            }
        }
        if (os < 7) {
            aA = *(const uint2*)(arow + (os + 1) * 64 + fq8);
            aB = *(const uint2*)(arow + (os + 1) * 64 + fq8 + 32);
        }

        bf16x8 ahA = *(bf16x8*)&vhA, alA = *(bf16x8*)&vlA;
        bf16x8 ahB = *(bf16x8*)&vhB, alB = *(bf16x8*)&vlB;

        #pragma unroll
        for (int n = 0; n < 8; ++n) {
            bf16x8 vA = *(bf16x8*)(vb + (n * 2 + 0) * 512 + lane * 8);
            bf16x8 vB = *(bf16x8*)(vb + (n * 2 + 1) * 512 + lane * 8);
            acc[n] = __builtin_amdgcn_mfma_f32_16x16x32_bf16(ahA, vA, acc[n], 0, 0, 0);
            acc[n] = __builtin_amdgcn_mfma_f32_16x16x32_bf16(alA, vA, acc[n], 0, 0, 0);
            acc[n] = __builtin_amdgcn_mfma_f32_16x16x32_bf16(ahB, vB, acc[n], 0, 0, 0);
            acc[n] = __builtin_amdgcn_mfma_f32_16x16x32_bf16(alB, vB, acc[n], 0, 0, 0);
        }
        __syncthreads();
    }
#undef STAGE_V

    rsum += __shfl_xor(rsum, 16);
    rsum += __shfl_xor(rsum, 32);

    #pragma unroll
    for (int rr = 0; rr < 4; ++rr) {
        const int row = fq * 4 + rr;
        const float inv = 1.0f / __shfl(rsum, row);
        #pragma unroll
        for (int n = 0; n < 8; ++n) {
            out[(size_t)(b * 512 + i0 + row) * 1024 + h * 128 + n * 16 + fr] =
                fmaxf(acc[n][rr] * inv, 0.f);
        }
    }
}

// ---------------------------------------------------------------------------
extern "C" void kernel_launch(void* const* d_in, const int* in_sizes, int n_in,
                              void* d_out, int out_size, void* d_ws, size_t ws_size,
                              hipStream_t stream) {
    const float* x   = (const float*)d_in[0];
    const int*   adj = (const int*)d_in[1];
    const float* nm  = (const float*)d_in[2];
    const float* W   = (const float*)d_in[3];
    const float* a1  = (const float*)d_in[4];
    const float* a2  = (const float*)d_in[5];
    float* out = (float*)d_out;
    char* wsb = (char*)d_ws;

    unsigned short* Bh   = (unsigned short*)(wsb);
    unsigned short* Bl   = (unsigned short*)(wsb + 2359296);
    float*          LR   = (float*)(wsb + 21495808);
    unsigned short* Vt   = (unsigned short*)(wsb + 23068672);
    unsigned char*  adjB = (unsigned char*)(wsb + 39845888);

    hipLaunchKernelGGL(prep_kernel, dim3(1616), dim3(256), 0, stream, adj, W, a1, a2, Bh, Bl, adjB);
    hipLaunchKernelGGL(mgemm, dim3(576), dim3(256), 0, stream, x, Bh, Bl, nm, Vt, LR);
    hipLaunchKernelGGL(attn_kernel, dim3(1024), dim3(256), 0, stream, Vt, LR, adjB, out);
}

// Round 19
// 134.993 us; speedup vs baseline: 1.1149x; 1.1149x over previous
//
#include <hip/hip_runtime.h>

typedef __attribute__((ext_vector_type(8))) __bf16 bf16x8;
typedef __attribute__((ext_vector_type(8))) unsigned short u16x8;
typedef __attribute__((ext_vector_type(4))) unsigned short u16x4;
typedef __attribute__((ext_vector_type(4))) float f32x4;

#define NEGV (-1e30f)

// ---------------------------------------------------------------------------
// Workspace layout (bytes):
//  Bh  : [1152][1024] bf16  @ 0          (2,359,296)
//  Bl  : [1152][1024] bf16  @ 2359296    (2,359,296)
//  LR  : [48][8192]  f32    @ 21495808   (1,572,864)
//  Vt  : [8][16][128][512] bf16 @ 23068672 (16,777,216)  written by mgemm
//  adjB: [16][512][512] u8  @ 39845888   (4,194,304)
//  total 44,040,192 B
// ---------------------------------------------------------------------------

__device__ __forceinline__ unsigned short f2bf(float f) {
    unsigned int u = __float_as_uint(f);
    u += 0x7fffu + ((u >> 16) & 1u);
    return (unsigned short)(u >> 16);
}
__device__ __forceinline__ float b2f(unsigned short h) {
    return __uint_as_float(((unsigned int)h) << 16);
}
// RNE via hardware cvt (v_cvt_pk_bf16_f32); bitwise == f2bf on finite inputs.
__device__ __forceinline__ unsigned short f2bf_rn(float f) {
    union { __bf16 b; unsigned short u; } c;
    c.b = (__bf16)f;
    return c.u;
}

// ---------------------------------------------------------------------------
// Kernel 1: fused pack (tr + wa + zero).  grid 592.  [r17-verified]
// ---------------------------------------------------------------------------
__global__ __launch_bounds__(256) void pack_all(const float* __restrict__ W,
                                                const float* __restrict__ a1,
                                                const float* __restrict__ a2,
                                                unsigned short* __restrict__ Bh,
                                                unsigned short* __restrict__ Bl) {
    __shared__ float tile[64 * 133];
    const int bid = blockIdx.x;
    const int tid = threadIdx.x;

    if (bid < 128) {
        const int kt = bid & 15, h = bid >> 4;
        const int k0 = kt * 64;
        const float* wsrc = W + ((size_t)((h * 3 + 2) * 1024) + k0) * 128;

        #pragma unroll
        for (int rep = 0; rep < 8; ++rep) {
            int idx = rep * 256 + tid;
            int k = idx >> 5, dc = (idx & 31) * 4;
            float4 v = *(const float4*)(wsrc + (size_t)k * 128 + dc);
            tile[k * 133 + dc + 0] = v.x;
            tile[k * 133 + dc + 1] = v.y;
            tile[k * 133 + dc + 2] = v.z;
            tile[k * 133 + dc + 3] = v.w;
        }
        __syncthreads();
        #pragma unroll
        for (int rep = 0; rep < 4; ++rep) {
            int idx = rep * 256 + tid;
            int d = idx >> 3, kc = (idx & 7) * 8;
            u16x8 vh, vl;
            #pragma unroll
            for (int q = 0; q < 8; ++q) {
                float f = tile[(kc + q) * 133 + d];
                unsigned short hi = f2bf(f);
                vh[q] = hi;
                vl[q] = f2bf(f - b2f(hi));
            }
            size_t o = (size_t)(h * 128 + d) * 1024 + k0 + kc;
            *(u16x8*)(Bh + o) = vh;
            *(u16x8*)(Bl + o) = vl;
        }
    } else if (bid < 512) {
        const int b2 = bid - 128;
        const int kt = b2 & 15, ht = b2 >> 4;
        const int h = ht & 7, t = ht >> 3;
        const int k0 = kt * 64;
        const float* wsrc = W + ((size_t)((h * 3 + t) * 1024) + k0) * 128;

        #pragma unroll
        for (int rep = 0; rep < 8; ++rep) {
            int idx = rep * 256 + tid;
            int k = idx >> 5, dc = (idx & 31) * 4;
            float4 v = *(const float4*)(wsrc + (size_t)k * 128 + dc);
            tile[k * 133 + dc + 0] = v.x;
            tile[k * 133 + dc + 1] = v.y;
            tile[k * 133 + dc + 2] = v.z;
            tile[k * 133 + dc + 3] = v.w;
        }
        __syncthreads();
        if (tid < 128) {
            const int k = tid & 63, s = tid >> 6;
            const float* ar = (s ? a2 : a1) + (h * 3 + t) * 128;
            float acc = 0.f;
            #pragma unroll 4
            for (int d = 0; d < 128; ++d) acc += tile[k * 133 + d] * ar[d];
            unsigned short hi = f2bf(acc);
            size_t o = (size_t)(1024 + s * 24 + t * 8 + h) * 1024 + k0 + k;
            Bh[o] = hi;
            Bl[o] = f2bf(acc - b2f(hi));
        }
    } else {
        const int n = 1072 + (bid - 512);
        *(unsigned long long*)(Bh + (size_t)n * 1024 + tid * 4) = 0ull;
        *(unsigned long long*)(Bl + (size_t)n * 1024 + tid * 4) = 0ull;
    }
}

// ---------------------------------------------------------------------------
// Kernel 2: bf16x3 MFMA GEMM — r17-exact (verified 86us): 128x128 tile,
//   4 waves, 2-barrier loop, hw-cvt A path, Vt-direct epilogue.
// ---------------------------------------------------------------------------
__global__ __launch_bounds__(256, 3) void mgemm(const float* __restrict__ X,
                                                const unsigned short* __restrict__ Bh,
                                                const unsigned short* __restrict__ Bl,
                                                const float* __restrict__ nm,
                                                unsigned short* __restrict__ Vt,
                                                float* __restrict__ LR) {
    __shared__ unsigned short Ah[128 * 32];
    __shared__ unsigned short Al[128 * 32];
    __shared__ unsigned short Bhs[128 * 32];
    __shared__ unsigned short Bls[128 * 32];

    const int bid = blockIdx.x;                 // 0..575
    const int swz = (bid & 7) * 72 + (bid >> 3); // XCD-aware, bijective
    const int nt = swz % 9, mt = swz / 9;
    const int n0 = nt * 128, m0 = mt * 128;

    const int tid = threadIdx.x;
    const int lane = tid & 63, w = tid >> 6;
    const int wr = w >> 1, wc = w & 1;
    const int fr = lane & 15, fq = lane >> 4;

    f32x4 acc[4][4];
    #pragma unroll
    for (int m = 0; m < 4; ++m)
        #pragma unroll
        for (int n = 0; n < 4; ++n) acc[m][n] = (f32x4){0.f, 0.f, 0.f, 0.f};

    const int arow = tid >> 1, ahalf = tid & 1;
    const float* xs = X + (size_t)(m0 + arow) * 1024 + ahalf * 16;
    unsigned short* adh = Ah + arow * 32 + ahalf * 16;
    unsigned short* adl = Al + arow * 32 + ahalf * 16;

    for (int k0 = 0; k0 < 1024; k0 += 32) {
        __syncthreads();

        #pragma unroll
        for (int q = 0; q < 2; ++q) {
            const int s = q * 256 + tid;
            const int brow = s >> 2, bkb = s & 3;
            const unsigned short* gh = Bh + (size_t)(n0 + brow) * 1024 + k0 + bkb * 8;
            const unsigned short* gl = Bl + (size_t)(n0 + brow) * 1024 + k0 + bkb * 8;
            unsigned short* dh = Bhs + (q * 256 + w * 64) * 8;
            unsigned short* dl = Bls + (q * 256 + w * 64) * 8;
            __builtin_amdgcn_global_load_lds(
                (const __attribute__((address_space(1))) void*)gh,
                (__attribute__((address_space(3))) void*)dh, 16, 0, 0);
            __builtin_amdgcn_global_load_lds(
                (const __attribute__((address_space(1))) void*)gl,
                (__attribute__((address_space(3))) void*)dl, 16, 0, 0);
        }

        float xf[16];
        #pragma unroll
        for (int i = 0; i < 4; ++i) {
            float4 v = *(const float4*)(xs + k0 + i * 4);
            xf[i * 4 + 0] = v.x; xf[i * 4 + 1] = v.y;
            xf[i * 4 + 2] = v.z; xf[i * 4 + 3] = v.w;
        }
        u16x8 vh0, vh1, vl0, vl1;
        #pragma unroll
        for (int i = 0; i < 8; ++i) {
            unsigned short hi = f2bf_rn(xf[i]);
            vh0[i] = hi;
            vl0[i] = f2bf_rn(xf[i] - b2f(hi));
        }
        #pragma unroll
        for (int i = 0; i < 8; ++i) {
            unsigned short hi = f2bf_rn(xf[8 + i]);
            vh1[i] = hi;
            vl1[i] = f2bf_rn(xf[8 + i] - b2f(hi));
        }
        *(u16x8*)(adh) = vh0;
        *(u16x8*)(adh + 8) = vh1;
        *(u16x8*)(adl) = vl0;
        *(u16x8*)(adl + 8) = vl1;

        __syncthreads();

        bf16x8 amh[4], bnh[4];
        #pragma unroll
        for (int m = 0; m < 4; ++m)
            amh[m] = *(bf16x8*)(Ah + (wr * 64 + m * 16 + fr) * 32 + fq * 8);
        #pragma unroll
        for (int n = 0; n < 4; ++n)
            bnh[n] = *(bf16x8*)(Bhs + (wc * 64 + n * 16 + fr) * 32 + fq * 8);
        #pragma unroll
        for (int m = 0; m < 4; ++m)
            #pragma unroll
            for (int n = 0; n < 4; ++n)
                acc[m][n] = __builtin_amdgcn_mfma_f32_16x16x32_bf16(amh[m], bnh[n], acc[m][n], 0, 0, 0);

        bf16x8 bnl[4];
        #pragma unroll
        for (int n = 0; n < 4; ++n)
            bnl[n] = *(bf16x8*)(Bls + (wc * 64 + n * 16 + fr) * 32 + fq * 8);
        #pragma unroll
        for (int m = 0; m < 4; ++m)
            #pragma unroll
            for (int n = 0; n < 4; ++n)
                acc[m][n] = __builtin_amdgcn_mfma_f32_16x16x32_bf16(amh[m], bnl[n], acc[m][n], 0, 0, 0);

        bf16x8 aml[4];
        #pragma unroll
        for (int m = 0; m < 4; ++m)
            aml[m] = *(bf16x8*)(Al + (wr * 64 + m * 16 + fr) * 32 + fq * 8);
        #pragma unroll
        for (int m = 0; m < 4; ++m)
            #pragma unroll
            for (int n = 0; n < 4; ++n)
                acc[m][n] = __builtin_amdgcn_mfma_f32_16x16x32_bf16(aml[m], bnh[n], acc[m][n], 0, 0, 0);
    }

    // ---- epilogue: C/D layout col=lane&15, row=(lane>>4)*4+reg
    if (nt < 8) {
        const int b_ = (mt * 128) >> 9;
        const int jb0 = (mt & 3) * 128;
        unsigned short* vtw = Vt + (size_t)(nt * 16 + b_) * 128 * 512;
        #pragma unroll
        for (int m = 0; m < 4; ++m) {
            const int jb = jb0 + wr * 64 + m * 16 + fq * 4;
            float mk[4];
            #pragma unroll
            for (int r = 0; r < 4; ++r)
                mk[r] = nm[m0 + wr * 64 + m * 16 + fq * 4 + r];
            #pragma unroll
            for (int n = 0; n < 4; ++n) {
                const int d = wc * 64 + n * 16 + fr;
                u16x4 pk;
                #pragma unroll
                for (int r = 0; r < 4; ++r) pk[r] = f2bf_rn(acc[m][n][r] * mk[r]);
                *(u16x4*)(vtw + (size_t)d * 512 + jb) = pk;
            }
        }
    } else {
        #pragma unroll
        for (int m = 0; m < 4; ++m) {
            #pragma unroll
            for (int r = 0; r < 4; ++r) {
                const int R = m0 + wr * 64 + m * 16 + fq * 4 + r;
                #pragma unroll
                for (int n = 0; n < 4; ++n) {
                    const int c = wc * 64 + n * 16 + fr;
                    if (c < 48) LR[(size_t)c * 8192 + R] = acc[m][n][r];
                }
            }
        }
    }
}

// ---------------------------------------------------------------------------
// Kernel 3b: adj int32 -> byte array adjB  [verified]
// ---------------------------------------------------------------------------
__global__ __launch_bounds__(256) void adjb_kernel(const int* __restrict__ adj,
                                                   unsigned char* __restrict__ adjB) {
    const int idx = blockIdx.x * 256 + threadIdx.x;
    const int4* s = (const int4*)(adj + (size_t)idx * 16);
    int4 v0 = s[0], v1 = s[1], v2 = s[2], v3 = s[3];
    union { unsigned char c[16]; int4 v; } o;
    o.c[0] = (unsigned char)v0.x; o.c[1] = (unsigned char)v0.y;
    o.c[2] = (unsigned char)v0.z; o.c[3] = (unsigned char)v0.w;
    o.c[4] = (unsigned char)v1.x; o.c[5] = (unsigned char)v1.y;
    o.c[6] = (unsigned char)v1.z; o.c[7] = (unsigned char)v1.w;
    o.c[8] = (unsigned char)v2.x; o.c[9] = (unsigned char)v2.y;
    o.c[10] = (unsigned char)v2.z; o.c[11] = (unsigned char)v2.w;
    o.c[12] = (unsigned char)v3.x; o.c[13] = (unsigned char)v3.y;
    o.c[14] = (unsigned char)v3.z; o.c[15] = (unsigned char)v3.w;
    *(int4*)(adjB + (size_t)idx * 16) = o.v;
}

// ---------------------------------------------------------------------------
// Kernel 4: fused attn — r17-exact (verified)
// ---------------------------------------------------------------------------
__global__ __launch_bounds__(256, 4) void attn_kernel(const unsigned short* __restrict__ Vt,
                                                      const float* __restrict__ LR,
                                                      const unsigned char* __restrict__ adjB,
                                                      float* __restrict__ out) {
    __shared__ __align__(16) unsigned short Vb[2][16 * 512];
    __shared__ __align__(16) float rt[3 * 512];

    const int bid = blockIdx.x;
    const int itg = bid >> 7, hb = bid & 127, h = hb >> 4, b = hb & 15;
    const int tid = threadIdx.x, w = tid >> 6, lane = tid & 63;
    const int fr = lane & 15, fq = lane >> 4;
    const int i0 = (itg * 4 + w) * 16;
    const int fq8 = fq * 8;

    for (int idx = tid; idx < 1536; idx += 256) {
        int t = idx >> 9, j = idx & 511;
        rt[idx] = LR[(size_t)(24 + t * 8 + h) * 8192 + b * 512 + j];
    }
    const float lf0 = LR[(size_t)(h) * 8192 + b * 512 + i0 + fr];
    const float lf1 = LR[(size_t)(8 + h) * 8192 + b * 512 + i0 + fr];
    const float lf2 = LR[(size_t)(16 + h) * 8192 + b * 512 + i0 + fr];
    const unsigned char* arow = adjB + (size_t)(b * 512 + i0 + fr) * 512;
    const unsigned short* vt = Vt + (size_t)(h * 16 + b) * 128 * 512;

#define STAGE_V(bufp, os_) do {                                                   \
        _Pragma("unroll")                                                          \
        for (int q_ = 0; q_ < 4; ++q_) {                                           \
            const int nh_ = q_ * 4 + w;                                            \
            const unsigned short* src_ = vt + (size_t)((nh_ >> 1) * 16 + fr) * 512 \
                                          + (os_) * 64 + (nh_ & 1) * 32 + fq8;     \
            unsigned short* dst_ = (bufp) + nh_ * 512;                             \
            __builtin_amdgcn_global_load_lds(                                      \
                (const __attribute__((address_space(1))) void*)src_,               \
                (__attribute__((address_space(3))) void*)dst_, 16, 0, 0);          \
        }                                                                          \
    } while (0)

    STAGE_V(&Vb[0][0], 0);
    uint2 aA = *(const uint2*)(arow + fq8);
    uint2 aB = *(const uint2*)(arow + fq8 + 32);

    f32x4 acc[8];
    #pragma unroll
    for (int n = 0; n < 8; ++n) acc[n] = (f32x4){0.f, 0.f, 0.f, 0.f};
    float rsum = 0.f;

    __syncthreads();

    #pragma unroll 1
    for (int os = 0; os < 8; ++os) {
        unsigned short* vb = &Vb[os & 1][0];
        if (os < 7) STAGE_V(&Vb[(os & 1) ^ 1][0], os + 1);

        const int jA = os * 64 + fq8;
        const int jB = jA + 32;

        u16x8 vhA, vlA, vhB, vlB;
        {
            float4 r0a = *(const float4*)(rt + jA), r0b = *(const float4*)(rt + jA + 4);
            float4 r1a = *(const float4*)(rt + 512 + jA), r1b = *(const float4*)(rt + 512 + jA + 4);
            float4 r2a = *(const float4*)(rt + 1024 + jA), r2b = *(const float4*)(rt + 1024 + jA + 4);
            float e0[8] = {r0a.x, r0a.y, r0a.z, r0a.w, r0b.x, r0b.y, r0b.z, r0b.w};
            float e1[8] = {r1a.x, r1a.y, r1a.z, r1a.w, r1b.x, r1b.y, r1b.z, r1b.w};
            float e2[8] = {r2a.x, r2a.y, r2a.z, r2a.w, r2b.x, r2b.y, r2b.z, r2b.w};
            #pragma unroll
            for (int q = 0; q < 8; ++q) {
                unsigned av = ((q < 4 ? aA.x : aA.y) >> (8 * (q & 3))) & 255u;
                float sb = (av == 1u) ? (lf0 + e0[q])
                         : (av == 2u) ? (lf1 + e1[q]) : (lf2 + e2[q]);
                float sv = fmaxf(sb, 0.f) + 0.2f * fminf(sb, 0.f);
                float p = (av != 0u) ? __expf(sv) : 0.f;
                rsum += p;
                unsigned short hi = f2bf_rn(p);
                vhA[q] = hi;
                vlA[q] = f2bf_rn(p - b2f(hi));
            }
        }
        {
            float4 r0a = *(const float4*)(rt + jB), r0b = *(const float4*)(rt + jB + 4);
            float4 r1a = *(const float4*)(rt + 512 + jB), r1b = *(const float4*)(rt + 512 + jB + 4);
            float4 r2a = *(const float4*)(rt + 1024 + jB), r2b = *(const float4*)(rt + 1024 + jB + 4);
            float e0[8] = {r0a.x, r0a.y, r0a.z, r0a.w, r0b.x, r0b.y, r0b.z, r0b.w};
            float e1[8] = {r1a.x, r1a.y, r1a.z, r1a.w, r1b.x, r1b.y, r1b.z, r1b.w};
            float e2[8] = {r2a.x, r2a.y, r2a.z, r2a.w, r2b.x, r2b.y, r2b.z, r2b.w};
            #pragma unroll
            for (int q = 0; q < 8; ++q) {
                unsigned av = ((q < 4 ? aB.x : aB.y) >> (8 * (q & 3))) & 255u;
                float sb = (av == 1u) ? (lf0 + e0[q])
                         : (av == 2u) ? (lf1 + e1[q]) : (lf2 + e2[q]);
                float sv = fmaxf(sb, 0.f) + 0.2f * fminf(sb, 0.f);
                float p = (av != 0u) ? __expf(sv) : 0.f;
                rsum += p;
                unsigned short hi = f2bf_rn(p);
                vhB[q] = hi;
                vlB[q] = f2bf_rn(p - b2f(hi));
            }
        }
        if (os < 7) {
            aA = *(const uint2*)(arow + (os + 1) * 64 + fq8);
            aB = *(const uint2*)(arow + (os + 1) * 64 + fq8 + 32);
        }

        bf16x8 ahA = *(bf16x8*)&vhA, alA = *(bf16x8*)&vlA;
        bf16x8 ahB = *(bf16x8*)&vhB, alB = *(bf16x8*)&vlB;

        #pragma unroll
        for (int n = 0; n < 8; ++n) {
            bf16x8 vA = *(bf16x8*)(vb + (n * 2 + 0) * 512 + lane * 8);
            bf16x8 vB = *(bf16x8*)(vb + (n * 2 + 1) * 512 + lane * 8);
            acc[n] = __builtin_amdgcn_mfma_f32_16x16x32_bf16(ahA, vA, acc[n], 0, 0, 0);
            acc[n] = __builtin_amdgcn_mfma_f32_16x16x32_bf16(alA, vA, acc[n], 0, 0, 0);
            acc[n] = __builtin_amdgcn_mfma_f32_16x16x32_bf16(ahB, vB, acc[n], 0, 0, 0);
            acc[n] = __builtin_amdgcn_mfma_f32_16x16x32_bf16(alB, vB, acc[n], 0, 0, 0);
        }
        __syncthreads();
    }
#undef STAGE_V

    rsum += __shfl_xor(rsum, 16);
    rsum += __shfl_xor(rsum, 32);

    #pragma unroll
    for (int rr = 0; rr < 4; ++rr) {
        const int row = fq * 4 + rr;
        const float inv = 1.0f / __shfl(rsum, row);
        #pragma unroll
        for (int n = 0; n < 8; ++n) {
            out[(size_t)(b * 512 + i0 + row) * 1024 + h * 128 + n * 16 + fr] =
                fmaxf(acc[n][rr] * inv, 0.f);
        }
    }
}

// ---------------------------------------------------------------------------
extern "C" void kernel_launch(void* const* d_in, const int* in_sizes, int n_in,
                              void* d_out, int out_size, void* d_ws, size_t ws_size,
                              hipStream_t stream) {
    const float* x   = (const float*)d_in[0];
    const int*   adj = (const int*)d_in[1];
    const float* nm  = (const float*)d_in[2];
    const float* W   = (const float*)d_in[3];
    const float* a1  = (const float*)d_in[4];
    const float* a2  = (const float*)d_in[5];
    float* out = (float*)d_out;
    char* wsb = (char*)d_ws;

    unsigned short* Bh   = (unsigned short*)(wsb);
    unsigned short* Bl   = (unsigned short*)(wsb + 2359296);
    float*          LR   = (float*)(wsb + 21495808);
    unsigned short* Vt   = (unsigned short*)(wsb + 23068672);
    unsigned char*  adjB = (unsigned char*)(wsb + 39845888);

    hipLaunchKernelGGL(adjb_kernel, dim3(1024), dim3(256), 0, stream, adj, adjB);
    hipLaunchKernelGGL(pack_all, dim3(592), dim3(256), 0, stream, W, a1, a2, Bh, Bl);
    hipLaunchKernelGGL(mgemm, dim3(576), dim3(256), 0, stream, x, Bh, Bl, nm, Vt, LR);
    hipLaunchKernelGGL(attn_kernel, dim3(1024), dim3(256), 0, stream, Vt, LR, adjB, out);
}

// Round 20
// 119.806 us; speedup vs baseline: 1.2562x; 1.1268x over previous
//
#include <hip/hip_runtime.h>

typedef __attribute__((ext_vector_type(8))) _Float16 half8;
typedef __attribute__((ext_vector_type(8))) unsigned short u16x8;
typedef __attribute__((ext_vector_type(4))) unsigned short u16x4;
typedef __attribute__((ext_vector_type(4))) float f32x4;

#define NEGV (-1e30f)

// ---------------------------------------------------------------------------
// Workspace layout (bytes):
//  Bf  : [1152][1024] fp16 @ 0          (2,359,296)   packed B (single fp16)
//  LR  : [48][8192]  f32   @ 21495808   (1,572,864)
//  Vt  : [8][16][128][512] fp16 @ 23068672 (16,777,216)  written by mgemm
//  adjB: [16][512][512] u8 @ 39845888   (4,194,304)
//  total 44,040,192 B
// ---------------------------------------------------------------------------

__device__ __forceinline__ unsigned short f2h(float f) {
    union { _Float16 h; unsigned short u; } c;
    c.h = (_Float16)f;
    return c.u;
}
__device__ __forceinline__ float h2f(unsigned short u) {
    union { _Float16 h; unsigned short u; } c;
    c.u = u;
    return (float)c.h;
}

// ---------------------------------------------------------------------------
// Kernel 1: fused pack (tr + wa + zero) -> single fp16 B.  grid 592.
// ---------------------------------------------------------------------------
__global__ __launch_bounds__(256) void pack_all(const float* __restrict__ W,
                                                const float* __restrict__ a1,
                                                const float* __restrict__ a2,
                                                unsigned short* __restrict__ Bf) {
    __shared__ float tile[64 * 133];
    const int bid = blockIdx.x;
    const int tid = threadIdx.x;

    if (bid < 128) {
        const int kt = bid & 15, h = bid >> 4;
        const int k0 = kt * 64;
        const float* wsrc = W + ((size_t)((h * 3 + 2) * 1024) + k0) * 128;

        #pragma unroll
        for (int rep = 0; rep < 8; ++rep) {
            int idx = rep * 256 + tid;
            int k = idx >> 5, dc = (idx & 31) * 4;
            float4 v = *(const float4*)(wsrc + (size_t)k * 128 + dc);
            tile[k * 133 + dc + 0] = v.x;
            tile[k * 133 + dc + 1] = v.y;
            tile[k * 133 + dc + 2] = v.z;
            tile[k * 133 + dc + 3] = v.w;
        }
        __syncthreads();
        #pragma unroll
        for (int rep = 0; rep < 4; ++rep) {
            int idx = rep * 256 + tid;
            int d = idx >> 3, kc = (idx & 7) * 8;
            u16x8 vh;
            #pragma unroll
            for (int q = 0; q < 8; ++q) vh[q] = f2h(tile[(kc + q) * 133 + d]);
            *(u16x8*)(Bf + (size_t)(h * 128 + d) * 1024 + k0 + kc) = vh;
        }
    } else if (bid < 512) {
        const int b2 = bid - 128;
        const int kt = b2 & 15, ht = b2 >> 4;
        const int h = ht & 7, t = ht >> 3;
        const int k0 = kt * 64;
        const float* wsrc = W + ((size_t)((h * 3 + t) * 1024) + k0) * 128;

        #pragma unroll
        for (int rep = 0; rep < 8; ++rep) {
            int idx = rep * 256 + tid;
            int k = idx >> 5, dc = (idx & 31) * 4;
            float4 v = *(const float4*)(wsrc + (size_t)k * 128 + dc);
            tile[k * 133 + dc + 0] = v.x;
            tile[k * 133 + dc + 1] = v.y;
            tile[k * 133 + dc + 2] = v.z;
            tile[k * 133 + dc + 3] = v.w;
        }
        __syncthreads();
        if (tid < 128) {
            const int k = tid & 63, s = tid >> 6;
            const float* ar = (s ? a2 : a1) + (h * 3 + t) * 128;
            float acc = 0.f;
            #pragma unroll 4
            for (int d = 0; d < 128; ++d) acc += tile[k * 133 + d] * ar[d];
            Bf[(size_t)(1024 + s * 24 + t * 8 + h) * 1024 + k0 + k] = f2h(acc);
        }
    } else {
        const int n = 1072 + (bid - 512);
        *(unsigned long long*)(Bf + (size_t)n * 1024 + tid * 4) = 0ull;
    }
}

// ---------------------------------------------------------------------------
// Kernel 2: fp16 MFMA GEMM — r17 schedule (proven), fp16 datatypes:
//   B single fp16 (2 gloads/step, 8KB), X hi/lo fp16 split in regs,
//   32 mfma_f32_16x16x32_f16 per step (2 passes), LDS 24KB.
//   Epilogue: Vt fp16 direct, LR f32.
// ---------------------------------------------------------------------------
__global__ __launch_bounds__(256, 3) void mgemm(const float* __restrict__ X,
                                                const unsigned short* __restrict__ Bf,
                                                const float* __restrict__ nm,
                                                unsigned short* __restrict__ Vt,
                                                float* __restrict__ LR) {
    __shared__ unsigned short Ah[128 * 32];
    __shared__ unsigned short Al[128 * 32];
    __shared__ unsigned short Bfs[128 * 32];

    const int bid = blockIdx.x;                 // 0..575
    const int swz = (bid & 7) * 72 + (bid >> 3); // XCD-aware, bijective
    const int nt = swz % 9, mt = swz / 9;
    const int n0 = nt * 128, m0 = mt * 128;

    const int tid = threadIdx.x;
    const int lane = tid & 63, w = tid >> 6;
    const int wr = w >> 1, wc = w & 1;
    const int fr = lane & 15, fq = lane >> 4;

    f32x4 acc[4][4];
    #pragma unroll
    for (int m = 0; m < 4; ++m)
        #pragma unroll
        for (int n = 0; n < 4; ++n) acc[m][n] = (f32x4){0.f, 0.f, 0.f, 0.f};

    const int arow = tid >> 1, ahalf = tid & 1;
    const float* xs = X + (size_t)(m0 + arow) * 1024 + ahalf * 16;
    unsigned short* adh = Ah + arow * 32 + ahalf * 16;
    unsigned short* adl = Al + arow * 32 + ahalf * 16;

    for (int k0 = 0; k0 < 1024; k0 += 32) {
        __syncthreads();

        // ---- B tile: single fp16, 2 gload rounds (8KB)
        #pragma unroll
        for (int q = 0; q < 2; ++q) {
            const int s = q * 256 + tid;
            const int brow = s >> 2, bkb = s & 3;
            const unsigned short* g = Bf + (size_t)(n0 + brow) * 1024 + k0 + bkb * 8;
            unsigned short* d = Bfs + (q * 256 + w * 64) * 8;
            __builtin_amdgcn_global_load_lds(
                (const __attribute__((address_space(1))) void*)g,
                (__attribute__((address_space(3))) void*)d, 16, 0, 0);
        }

        // ---- A tile: f32 load -> fp16 hi/lo split -> ds_write
        float xf[16];
        #pragma unroll
        for (int i = 0; i < 4; ++i) {
            float4 v = *(const float4*)(xs + k0 + i * 4);
            xf[i * 4 + 0] = v.x; xf[i * 4 + 1] = v.y;
            xf[i * 4 + 2] = v.z; xf[i * 4 + 3] = v.w;
        }
        u16x8 vh0, vh1, vl0, vl1;
        #pragma unroll
        for (int i = 0; i < 8; ++i) {
            unsigned short hi = f2h(xf[i]);
            vh0[i] = hi;
            vl0[i] = f2h(xf[i] - h2f(hi));
        }
        #pragma unroll
        for (int i = 0; i < 8; ++i) {
            unsigned short hi = f2h(xf[8 + i]);
            vh1[i] = hi;
            vl1[i] = f2h(xf[8 + i] - h2f(hi));
        }
        *(u16x8*)(adh) = vh0;
        *(u16x8*)(adh + 8) = vh1;
        *(u16x8*)(adl) = vl0;
        *(u16x8*)(adl + 8) = vl1;

        __syncthreads();

        // ---- fragments + 32 MFMAs (2 passes)
        half8 amh[4], bn[4];
        #pragma unroll
        for (int m = 0; m < 4; ++m)
            amh[m] = *(half8*)(Ah + (wr * 64 + m * 16 + fr) * 32 + fq * 8);
        #pragma unroll
        for (int n = 0; n < 4; ++n)
            bn[n] = *(half8*)(Bfs + (wc * 64 + n * 16 + fr) * 32 + fq * 8);
        #pragma unroll
        for (int m = 0; m < 4; ++m)
            #pragma unroll
            for (int n = 0; n < 4; ++n)
                acc[m][n] = __builtin_amdgcn_mfma_f32_16x16x32_f16(amh[m], bn[n], acc[m][n], 0, 0, 0);

        half8 aml[4];
        #pragma unroll
        for (int m = 0; m < 4; ++m)
            aml[m] = *(half8*)(Al + (wr * 64 + m * 16 + fr) * 32 + fq * 8);
        #pragma unroll
        for (int m = 0; m < 4; ++m)
            #pragma unroll
            for (int n = 0; n < 4; ++n)
                acc[m][n] = __builtin_amdgcn_mfma_f32_16x16x32_f16(aml[m], bn[n], acc[m][n], 0, 0, 0);
    }

    // ---- epilogue: C/D layout col=lane&15, row=(lane>>4)*4+reg
    if (nt < 8) {
        const int b_ = (mt * 128) >> 9;
        const int jb0 = (mt & 3) * 128;
        unsigned short* vtw = Vt + (size_t)(nt * 16 + b_) * 128 * 512;
        #pragma unroll
        for (int m = 0; m < 4; ++m) {
            const int jb = jb0 + wr * 64 + m * 16 + fq * 4;
            float mk[4];
            #pragma unroll
            for (int r = 0; r < 4; ++r)
                mk[r] = nm[m0 + wr * 64 + m * 16 + fq * 4 + r];
            #pragma unroll
            for (int n = 0; n < 4; ++n) {
                const int d = wc * 64 + n * 16 + fr;
                u16x4 pk;
                #pragma unroll
                for (int r = 0; r < 4; ++r) pk[r] = f2h(acc[m][n][r] * mk[r]);
                *(u16x4*)(vtw + (size_t)d * 512 + jb) = pk;
            }
        }
    } else {
        #pragma unroll
        for (int m = 0; m < 4; ++m) {
            #pragma unroll
            for (int r = 0; r < 4; ++r) {
                const int R = m0 + wr * 64 + m * 16 + fq * 4 + r;
                #pragma unroll
                for (int n = 0; n < 4; ++n) {
                    const int c = wc * 64 + n * 16 + fr;
                    if (c < 48) LR[(size_t)c * 8192 + R] = acc[m][n][r];
                }
            }
        }
    }
}

// ---------------------------------------------------------------------------
// Kernel 3b: adj int32 -> byte array adjB  [verified, unchanged]
// ---------------------------------------------------------------------------
__global__ __launch_bounds__(256) void adjb_kernel(const int* __restrict__ adj,
                                                   unsigned char* __restrict__ adjB) {
    const int idx = blockIdx.x * 256 + threadIdx.x;
    const int4* s = (const int4*)(adj + (size_t)idx * 16);
    int4 v0 = s[0], v1 = s[1], v2 = s[2], v3 = s[3];
    union { unsigned char c[16]; int4 v; } o;
    o.c[0] = (unsigned char)v0.x; o.c[1] = (unsigned char)v0.y;
    o.c[2] = (unsigned char)v0.z; o.c[3] = (unsigned char)v0.w;
    o.c[4] = (unsigned char)v1.x; o.c[5] = (unsigned char)v1.y;
    o.c[6] = (unsigned char)v1.z; o.c[7] = (unsigned char)v1.w;
    o.c[8] = (unsigned char)v2.x; o.c[9] = (unsigned char)v2.y;
    o.c[10] = (unsigned char)v2.z; o.c[11] = (unsigned char)v2.w;
    o.c[12] = (unsigned char)v3.x; o.c[13] = (unsigned char)v3.y;
    o.c[14] = (unsigned char)v3.z; o.c[15] = (unsigned char)v3.w;
    *(int4*)(adjB + (size_t)idx * 16) = o.v;
}

// ---------------------------------------------------------------------------
// Kernel 4: fused attn — r17 schedule (verified), fp16 V/P + f16 MFMA.
// ---------------------------------------------------------------------------
__global__ __launch_bounds__(256, 4) void attn_kernel(const unsigned short* __restrict__ Vt,
                                                      const float* __restrict__ LR,
                                                      const unsigned char* __restrict__ adjB,
                                                      float* __restrict__ out) {
    __shared__ __align__(16) unsigned short Vb[2][16 * 512];
    __shared__ __align__(16) float rt[3 * 512];

    const int bid = blockIdx.x;
    const int itg = bid >> 7, hb = bid & 127, h = hb >> 4, b = hb & 15;
    const int tid = threadIdx.x, w = tid >> 6, lane = tid & 63;
    const int fr = lane & 15, fq = lane >> 4;
    const int i0 = (itg * 4 + w) * 16;
    const int fq8 = fq * 8;

    for (int idx = tid; idx < 1536; idx += 256) {
        int t = idx >> 9, j = idx & 511;
        rt[idx] = LR[(size_t)(24 + t * 8 + h) * 8192 + b * 512 + j];
    }
    const float lf0 = LR[(size_t)(h) * 8192 + b * 512 + i0 + fr];
    const float lf1 = LR[(size_t)(8 + h) * 8192 + b * 512 + i0 + fr];
    const float lf2 = LR[(size_t)(16 + h) * 8192 + b * 512 + i0 + fr];
    const unsigned char* arow = adjB + (size_t)(b * 512 + i0 + fr) * 512;
    const unsigned short* vt = Vt + (size_t)(h * 16 + b) * 128 * 512;

#define STAGE_V(bufp, os_) do {                                                   \
        _Pragma("unroll")                                                          \
        for (int q_ = 0; q_ < 4; ++q_) {                                           \
            const int nh_ = q_ * 4 + w;                                            \
            const unsigned short* src_ = vt + (size_t)((nh_ >> 1) * 16 + fr) * 512 \
                                          + (os_) * 64 + (nh_ & 1) * 32 + fq8;     \
            unsigned short* dst_ = (bufp) + nh_ * 512;                             \
            __builtin_amdgcn_global_load_lds(                                      \
                (const __attribute__((address_space(1))) void*)src_,               \
                (__attribute__((address_space(3))) void*)dst_, 16, 0, 0);          \
        }                                                                          \
    } while (0)

    STAGE_V(&Vb[0][0], 0);
    uint2 aA = *(const uint2*)(arow + fq8);
    uint2 aB = *(const uint2*)(arow + fq8 + 32);

    f32x4 acc[8];
    #pragma unroll
    for (int n = 0; n < 8; ++n) acc[n] = (f32x4){0.f, 0.f, 0.f, 0.f};
    float rsum = 0.f;

    __syncthreads();

    #pragma unroll 1
    for (int os = 0; os < 8; ++os) {
        unsigned short* vb = &Vb[os & 1][0];
        if (os < 7) STAGE_V(&Vb[(os & 1) ^ 1][0], os + 1);

        const int jA = os * 64 + fq8;
        const int jB = jA + 32;

        u16x8 vhA, vlA, vhB, vlB;
        {
            float4 r0a = *(const float4*)(rt + jA), r0b = *(const float4*)(rt + jA + 4);
            float4 r1a = *(const float4*)(rt + 512 + jA), r1b = *(const float4*)(rt + 512 + jA + 4);
            float4 r2a = *(const float4*)(rt + 1024 + jA), r2b = *(const float4*)(rt + 1024 + jA + 4);
            float e0[8] = {r0a.x, r0a.y, r0a.z, r0a.w, r0b.x, r0b.y, r0b.z, r0b.w};
            float e1[8] = {r1a.x, r1a.y, r1a.z, r1a.w, r1b.x, r1b.y, r1b.z, r1b.w};
            float e2[8] = {r2a.x, r2a.y, r2a.z, r2a.w, r2b.x, r2b.y, r2b.z, r2b.w};
            #pragma unroll
            for (int q = 0; q < 8; ++q) {
                unsigned av = ((q < 4 ? aA.x : aA.y) >> (8 * (q & 3))) & 255u;
                float sb = (av == 1u) ? (lf0 + e0[q])
                         : (av == 2u) ? (lf1 + e1[q]) : (lf2 + e2[q]);
                float sv = fmaxf(sb, 0.f) + 0.2f * fminf(sb, 0.f);
                float p = (av != 0u) ? __expf(sv) : 0.f;
                rsum += p;
                unsigned short hi = f2h(p);
                vhA[q] = hi;
                vlA[q] = f2h(p - h2f(hi));
            }
        }
        {
            float4 r0a = *(const float4*)(rt + jB), r0b = *(const float4*)(rt + jB + 4);
            float4 r1a = *(const float4*)(rt + 512 + jB), r1b = *(const float4*)(rt + 512 + jB + 4);
            float4 r2a = *(const float4*)(rt + 1024 + jB), r2b = *(const float4*)(rt + 1024 + jB + 4);
            float e0[8] = {r0a.x, r0a.y, r0a.z, r0a.w, r0b.x, r0b.y, r0b.z, r0b.w};
            float e1[8] = {r1a.x, r1a.y, r1a.z, r1a.w, r1b.x, r1b.y, r1b.z, r1b.w};
            float e2[8] = {r2a.x, r2a.y, r2a.z, r2a.w, r2b.x, r2b.y, r2b.z, r2b.w};
            #pragma unroll
            for (int q = 0; q < 8; ++q) {
                unsigned av = ((q < 4 ? aB.x : aB.y) >> (8 * (q & 3))) & 255u;
                float sb = (av == 1u) ? (lf0 + e0[q])
                         : (av == 2u) ? (lf1 + e1[q]) : (lf2 + e2[q]);
                float sv = fmaxf(sb, 0.f) + 0.2f * fminf(sb, 0.f);
                float p = (av != 0u) ? __expf(sv) : 0.f;
                rsum += p;
                unsigned short hi = f2h(p);
                vhB[q] = hi;
                vlB[q] = f2h(p - h2f(hi));
            }
        }
        if (os < 7) {
            aA = *(const uint2*)(arow + (os + 1) * 64 + fq8);
            aB = *(const uint2*)(arow + (os + 1) * 64 + fq8 + 32);
        }

        half8 ahA = *(half8*)&vhA, alA = *(half8*)&vlA;
        half8 ahB = *(half8*)&vhB, alB = *(half8*)&vlB;

        #pragma unroll
        for (int n = 0; n < 8; ++n) {
            half8 vA = *(half8*)(vb + (n * 2 + 0) * 512 + lane * 8);
            half8 vB = *(half8*)(vb + (n * 2 + 1) * 512 + lane * 8);
            acc[n] = __builtin_amdgcn_mfma_f32_16x16x32_f16(ahA, vA, acc[n], 0, 0, 0);
            acc[n] = __builtin_amdgcn_mfma_f32_16x16x32_f16(alA, vA, acc[n], 0, 0, 0);
            acc[n] = __builtin_amdgcn_mfma_f32_16x16x32_f16(ahB, vB, acc[n], 0, 0, 0);
            acc[n] = __builtin_amdgcn_mfma_f32_16x16x32_f16(alB, vB, acc[n], 0, 0, 0);
        }
        __syncthreads();
    }
#undef STAGE_V

    rsum += __shfl_xor(rsum, 16);
    rsum += __shfl_xor(rsum, 32);

    #pragma unroll
    for (int rr = 0; rr < 4; ++rr) {
        const int row = fq * 4 + rr;
        const float inv = 1.0f / __shfl(rsum, row);
        #pragma unroll
        for (int n = 0; n < 8; ++n) {
            out[(size_t)(b * 512 + i0 + row) * 1024 + h * 128 + n * 16 + fr] =
                fmaxf(acc[n][rr] * inv, 0.f);
        }
    }
}

// ---------------------------------------------------------------------------
extern "C" void kernel_launch(void* const* d_in, const int* in_sizes, int n_in,
                              void* d_out, int out_size, void* d_ws, size_t ws_size,
                              hipStream_t stream) {
    const float* x   = (const float*)d_in[0];
    const int*   adj = (const int*)d_in[1];
    const float* nm  = (const float*)d_in[2];
    const float* W   = (const float*)d_in[3];
    const float* a1  = (const float*)d_in[4];
    const float* a2  = (const float*)d_in[5];
    float* out = (float*)d_out;
    char* wsb = (char*)d_ws;

    unsigned short* Bf   = (unsigned short*)(wsb);
    float*          LR   = (float*)(wsb + 21495808);
    unsigned short* Vt   = (unsigned short*)(wsb + 23068672);
    unsigned char*  adjB = (unsigned char*)(wsb + 39845888);

    hipLaunchKernelGGL(adjb_kernel, dim3(1024), dim3(256), 0, stream, adj, adjB);
    hipLaunchKernelGGL(pack_all, dim3(592), dim3(256), 0, stream, W, a1, a2, Bf);
    hipLaunchKernelGGL(mgemm, dim3(576), dim3(256), 0, stream, x, Bf, nm, Vt, LR);
    hipLaunchKernelGGL(attn_kernel, dim3(1024), dim3(256), 0, stream, Vt, LR, adjB, out);
}

// Round 21
// 116.872 us; speedup vs baseline: 1.2878x; 1.0251x over previous
//
#include <hip/hip_runtime.h>

typedef __attribute__((ext_vector_type(8))) _Float16 half8;
typedef __attribute__((ext_vector_type(8))) unsigned short u16x8;
typedef __attribute__((ext_vector_type(4))) unsigned short u16x4;
typedef __attribute__((ext_vector_type(4))) float f32x4;

#define NEGV (-1e30f)

// ---------------------------------------------------------------------------
// Workspace layout (bytes):
//  Bf  : [1152][1024] fp16 @ 0          (2,359,296)   packed B (single fp16)
//  LR  : [48][8192]  f32   @ 21495808   (1,572,864)
//  Vt  : [8][16][128][512] fp16 @ 23068672 (16,777,216)  written by mgemm
//  adjB: [16][512][512] u8 @ 39845888   (4,194,304)
//  total 44,040,192 B
// ---------------------------------------------------------------------------

__device__ __forceinline__ unsigned short f2h(float f) {
    union { _Float16 h; unsigned short u; } c;
    c.h = (_Float16)f;
    return c.u;
}
__device__ __forceinline__ float h2f(unsigned short u) {
    union { _Float16 h; unsigned short u; } c;
    c.u = u;
    return (float)c.h;
}

// ---------------------------------------------------------------------------
// Kernel 1: fused pack (tr + wa + zero) -> single fp16 B.  [r20-verified]
// ---------------------------------------------------------------------------
__global__ __launch_bounds__(256) void pack_all(const float* __restrict__ W,
                                                const float* __restrict__ a1,
                                                const float* __restrict__ a2,
                                                unsigned short* __restrict__ Bf) {
    __shared__ float tile[64 * 133];
    const int bid = blockIdx.x;
    const int tid = threadIdx.x;

    if (bid < 128) {
        const int kt = bid & 15, h = bid >> 4;
        const int k0 = kt * 64;
        const float* wsrc = W + ((size_t)((h * 3 + 2) * 1024) + k0) * 128;

        #pragma unroll
        for (int rep = 0; rep < 8; ++rep) {
            int idx = rep * 256 + tid;
            int k = idx >> 5, dc = (idx & 31) * 4;
            float4 v = *(const float4*)(wsrc + (size_t)k * 128 + dc);
            tile[k * 133 + dc + 0] = v.x;
            tile[k * 133 + dc + 1] = v.y;
            tile[k * 133 + dc + 2] = v.z;
            tile[k * 133 + dc + 3] = v.w;
        }
        __syncthreads();
        #pragma unroll
        for (int rep = 0; rep < 4; ++rep) {
            int idx = rep * 256 + tid;
            int d = idx >> 3, kc = (idx & 7) * 8;
            u16x8 vh;
            #pragma unroll
            for (int q = 0; q < 8; ++q) vh[q] = f2h(tile[(kc + q) * 133 + d]);
            *(u16x8*)(Bf + (size_t)(h * 128 + d) * 1024 + k0 + kc) = vh;
        }
    } else if (bid < 512) {
        const int b2 = bid - 128;
        const int kt = b2 & 15, ht = b2 >> 4;
        const int h = ht & 7, t = ht >> 3;
        const int k0 = kt * 64;
        const float* wsrc = W + ((size_t)((h * 3 + t) * 1024) + k0) * 128;

        #pragma unroll
        for (int rep = 0; rep < 8; ++rep) {
            int idx = rep * 256 + tid;
            int k = idx >> 5, dc = (idx & 31) * 4;
            float4 v = *(const float4*)(wsrc + (size_t)k * 128 + dc);
            tile[k * 133 + dc + 0] = v.x;
            tile[k * 133 + dc + 1] = v.y;
            tile[k * 133 + dc + 2] = v.z;
            tile[k * 133 + dc + 3] = v.w;
        }
        __syncthreads();
        if (tid < 128) {
            const int k = tid & 63, s = tid >> 6;
            const float* ar = (s ? a2 : a1) + (h * 3 + t) * 128;
            float acc = 0.f;
            #pragma unroll 4
            for (int d = 0; d < 128; ++d) acc += tile[k * 133 + d] * ar[d];
            Bf[(size_t)(1024 + s * 24 + t * 8 + h) * 1024 + k0 + k] = f2h(acc);
        }
    } else {
        const int n = 1072 + (bid - 512);
        *(unsigned long long*)(Bf + (size_t)n * 1024 + tid * 4) = 0ull;
    }
}

// ---------------------------------------------------------------------------
// Kernel 2: fp16 MFMA GEMM — r20 datatypes + DOUBLE-BUFFERED single-barrier
//   pipeline (48KB LDS -> 3 blocks/CU >= grid demand 2.25, unlike r13's 2):
//   per step: issue B gloads(t+1)->buf^1 + X loads(t+1)->regs FIRST,
//   compute(t) from buf^0 (8 frag reads + 32 f16 MFMA), convert+write A(t+1),
//   ONE barrier. Loads get the whole compute phase to land.
// ---------------------------------------------------------------------------
__global__ __launch_bounds__(256, 3) void mgemm(const float* __restrict__ X,
                                                const unsigned short* __restrict__ Bf,
                                                const float* __restrict__ nm,
                                                unsigned short* __restrict__ Vt,
                                                float* __restrict__ LR) {
    __shared__ unsigned short Ah[2][128 * 32];
    __shared__ unsigned short Al[2][128 * 32];
    __shared__ unsigned short Bfs[2][128 * 32];

    const int bid = blockIdx.x;                 // 0..575
    const int swz = (bid & 7) * 72 + (bid >> 3); // XCD-aware, bijective
    const int nt = swz % 9, mt = swz / 9;
    const int n0 = nt * 128, m0 = mt * 128;

    const int tid = threadIdx.x;
    const int lane = tid & 63, w = tid >> 6;
    const int wr = w >> 1, wc = w & 1;
    const int fr = lane & 15, fq = lane >> 4;

    f32x4 acc[4][4];
    #pragma unroll
    for (int m = 0; m < 4; ++m)
        #pragma unroll
        for (int n = 0; n < 4; ++n) acc[m][n] = (f32x4){0.f, 0.f, 0.f, 0.f};

    const int arow = tid >> 1, ahalf = tid & 1;
    const float* xs = X + (size_t)(m0 + arow) * 1024 + ahalf * 16;
    const int aoff = arow * 32 + ahalf * 16;

#define GLDB(kk, buf) do {                                                        \
        _Pragma("unroll")                                                          \
        for (int q_ = 0; q_ < 2; ++q_) {                                           \
            const int s_ = q_ * 256 + tid;                                         \
            const int brow_ = s_ >> 2, bkb_ = s_ & 3;                              \
            const unsigned short* g_ = Bf + (size_t)(n0 + brow_) * 1024 + (kk) + bkb_ * 8; \
            unsigned short* d_ = &Bfs[buf][(q_ * 256 + w * 64) * 8];               \
            __builtin_amdgcn_global_load_lds(                                      \
                (const __attribute__((address_space(1))) void*)g_,                 \
                (__attribute__((address_space(3))) void*)d_, 16, 0, 0);            \
        }                                                                          \
    } while (0)

#define CONVA(xa_, xb_, buf) do {                                                 \
        float xf_[8] = {(xa_).x, (xa_).y, (xa_).z, (xa_).w,                        \
                        (xb_).x, (xb_).y, (xb_).z, (xb_).w};                       \
        u16x8 vh_, vl_;                                                            \
        _Pragma("unroll")                                                          \
        for (int i_ = 0; i_ < 8; ++i_) {                                           \
            unsigned short hi_ = f2h(xf_[i_]);                                     \
            vh_[i_] = hi_;                                                         \
            vl_[i_] = f2h(xf_[i_] - h2f(hi_));                                     \
        }                                                                          \
        *(u16x8*)(&Ah[buf][aoff]) = vh_;                                           \
        *(u16x8*)(&Al[buf][aoff]) = vl_;                                           \
    } while (0)

#define CONVA2(xa_, xb_, buf) do {                                                \
        float xf_[8] = {(xa_).x, (xa_).y, (xa_).z, (xa_).w,                        \
                        (xb_).x, (xb_).y, (xb_).z, (xb_).w};                       \
        u16x8 vh_, vl_;                                                            \
        _Pragma("unroll")                                                          \
        for (int i_ = 0; i_ < 8; ++i_) {                                           \
            unsigned short hi_ = f2h(xf_[i_]);                                     \
            vh_[i_] = hi_;                                                         \
            vl_[i_] = f2h(xf_[i_] - h2f(hi_));                                     \
        }                                                                          \
        *(u16x8*)(&Ah[buf][aoff + 8]) = vh_;                                       \
        *(u16x8*)(&Al[buf][aoff + 8]) = vl_;                                       \
    } while (0)

    // ---- prologue: stage step 0 into buf 0
    GLDB(0, 0);
    {
        float4 xa = *(const float4*)(xs);
        float4 xb = *(const float4*)(xs + 4);
        float4 xc = *(const float4*)(xs + 8);
        float4 xd = *(const float4*)(xs + 12);
        CONVA(xa, xb, 0);
        CONVA2(xc, xd, 0);
    }
    __syncthreads();

    for (int k0 = 0; k0 < 1024; k0 += 32) {
        const int cur = (k0 >> 5) & 1;
        const int nxt = cur ^ 1;
        const bool more = (k0 < 992);

        // ---- issue next-step loads FIRST (latency hides under compute)
        float4 xa, xb, xc, xd;
        if (more) {
            GLDB(k0 + 32, nxt);
            xa = *(const float4*)(xs + k0 + 32);
            xb = *(const float4*)(xs + k0 + 36);
            xc = *(const float4*)(xs + k0 + 40);
            xd = *(const float4*)(xs + k0 + 44);
        }

        // ---- compute current step: 8 frag reads + 32 MFMA
        half8 amh[4], bn[4];
        #pragma unroll
        for (int m = 0; m < 4; ++m)
            amh[m] = *(half8*)(&Ah[cur][(wr * 64 + m * 16 + fr) * 32 + fq * 8]);
        #pragma unroll
        for (int n = 0; n < 4; ++n)
            bn[n] = *(half8*)(&Bfs[cur][(wc * 64 + n * 16 + fr) * 32 + fq * 8]);
        #pragma unroll
        for (int m = 0; m < 4; ++m)
            #pragma unroll
            for (int n = 0; n < 4; ++n)
                acc[m][n] = __builtin_amdgcn_mfma_f32_16x16x32_f16(amh[m], bn[n], acc[m][n], 0, 0, 0);

        half8 aml[4];
        #pragma unroll
        for (int m = 0; m < 4; ++m)
            aml[m] = *(half8*)(&Al[cur][(wr * 64 + m * 16 + fr) * 32 + fq * 8]);
        #pragma unroll
        for (int m = 0; m < 4; ++m)
            #pragma unroll
            for (int n = 0; n < 4; ++n)
                acc[m][n] = __builtin_amdgcn_mfma_f32_16x16x32_f16(aml[m], bn[n], acc[m][n], 0, 0, 0);

        // ---- convert + write next A (X regs arrived during compute)
        if (more) {
            CONVA(xa, xb, nxt);
            CONVA2(xc, xd, nxt);
        }

        __syncthreads();   // single barrier per step
    }
#undef GLDB
#undef CONVA
#undef CONVA2

    // ---- epilogue: C/D layout col=lane&15, row=(lane>>4)*4+reg
    if (nt < 8) {
        const int b_ = (mt * 128) >> 9;
        const int jb0 = (mt & 3) * 128;
        unsigned short* vtw = Vt + (size_t)(nt * 16 + b_) * 128 * 512;
        #pragma unroll
        for (int m = 0; m < 4; ++m) {
            const int jb = jb0 + wr * 64 + m * 16 + fq * 4;
            float mk[4];
            #pragma unroll
            for (int r = 0; r < 4; ++r)
                mk[r] = nm[m0 + wr * 64 + m * 16 + fq * 4 + r];
            #pragma unroll
            for (int n = 0; n < 4; ++n) {
                const int d = wc * 64 + n * 16 + fr;
                u16x4 pk;
                #pragma unroll
                for (int r = 0; r < 4; ++r) pk[r] = f2h(acc[m][n][r] * mk[r]);
                *(u16x4*)(vtw + (size_t)d * 512 + jb) = pk;
            }
        }
    } else {
        #pragma unroll
        for (int m = 0; m < 4; ++m) {
            #pragma unroll
            for (int r = 0; r < 4; ++r) {
                const int R = m0 + wr * 64 + m * 16 + fq * 4 + r;
                #pragma unroll
                for (int n = 0; n < 4; ++n) {
                    const int c = wc * 64 + n * 16 + fr;
                    if (c < 48) LR[(size_t)c * 8192 + R] = acc[m][n][r];
                }
            }
        }
    }
}

// ---------------------------------------------------------------------------
// Kernel 3b: adj int32 -> byte array adjB  [verified, unchanged]
// ---------------------------------------------------------------------------
__global__ __launch_bounds__(256) void adjb_kernel(const int* __restrict__ adj,
                                                   unsigned char* __restrict__ adjB) {
    const int idx = blockIdx.x * 256 + threadIdx.x;
    const int4* s = (const int4*)(adj + (size_t)idx * 16);
    int4 v0 = s[0], v1 = s[1], v2 = s[2], v3 = s[3];
    union { unsigned char c[16]; int4 v; } o;
    o.c[0] = (unsigned char)v0.x; o.c[1] = (unsigned char)v0.y;
    o.c[2] = (unsigned char)v0.z; o.c[3] = (unsigned char)v0.w;
    o.c[4] = (unsigned char)v1.x; o.c[5] = (unsigned char)v1.y;
    o.c[6] = (unsigned char)v1.z; o.c[7] = (unsigned char)v1.w;
    o.c[8] = (unsigned char)v2.x; o.c[9] = (unsigned char)v2.y;
    o.c[10] = (unsigned char)v2.z; o.c[11] = (unsigned char)v2.w;
    o.c[12] = (unsigned char)v3.x; o.c[13] = (unsigned char)v3.y;
    o.c[14] = (unsigned char)v3.z; o.c[15] = (unsigned char)v3.w;
    *(int4*)(adjB + (size_t)idx * 16) = o.v;
}

// ---------------------------------------------------------------------------
// Kernel 4: fused attn — r20-exact (verified 119.8us total)
// ---------------------------------------------------------------------------
__global__ __launch_bounds__(256, 4) void attn_kernel(const unsigned short* __restrict__ Vt,
                                                      const float* __restrict__ LR,
                                                      const unsigned char* __restrict__ adjB,
                                                      float* __restrict__ out) {
    __shared__ __align__(16) unsigned short Vb[2][16 * 512];
    __shared__ __align__(16) float rt[3 * 512];

    const int bid = blockIdx.x;
    const int itg = bid >> 7, hb = bid & 127, h = hb >> 4, b = hb & 15;
    const int tid = threadIdx.x, w = tid >> 6, lane = tid & 63;
    const int fr = lane & 15, fq = lane >> 4;
    const int i0 = (itg * 4 + w) * 16;
    const int fq8 = fq * 8;

    for (int idx = tid; idx < 1536; idx += 256) {
        int t = idx >> 9, j = idx & 511;
        rt[idx] = LR[(size_t)(24 + t * 8 + h) * 8192 + b * 512 + j];
    }
    const float lf0 = LR[(size_t)(h) * 8192 + b * 512 + i0 + fr];
    const float lf1 = LR[(size_t)(8 + h) * 8192 + b * 512 + i0 + fr];
    const float lf2 = LR[(size_t)(16 + h) * 8192 + b * 512 + i0 + fr];
    const unsigned char* arow = adjB + (size_t)(b * 512 + i0 + fr) * 512;
    const unsigned short* vt = Vt + (size_t)(h * 16 + b) * 128 * 512;

#define STAGE_V(bufp, os_) do {                                                   \
        _Pragma("unroll")                                                          \
        for (int q_ = 0; q_ < 4; ++q_) {                                           \
            const int nh_ = q_ * 4 + w;                                            \
            const unsigned short* src_ = vt + (size_t)((nh_ >> 1) * 16 + fr) * 512 \
                                          + (os_) * 64 + (nh_ & 1) * 32 + fq8;     \
            unsigned short* dst_ = (bufp) + nh_ * 512;                             \
            __builtin_amdgcn_global_load_lds(                                      \
                (const __attribute__((address_space(1))) void*)src_,               \
                (__attribute__((address_space(3))) void*)dst_, 16, 0, 0);          \
        }                                                                          \
    } while (0)

    STAGE_V(&Vb[0][0], 0);
    uint2 aA = *(const uint2*)(arow + fq8);
    uint2 aB = *(const uint2*)(arow + fq8 + 32);

    f32x4 acc[8];
    #pragma unroll
    for (int n = 0; n < 8; ++n) acc[n] = (f32x4){0.f, 0.f, 0.f, 0.f};
    float rsum = 0.f;

    __syncthreads();

    #pragma unroll 1
    for (int os = 0; os < 8; ++os) {
        unsigned short* vb = &Vb[os & 1][0];
        if (os < 7) STAGE_V(&Vb[(os & 1) ^ 1][0], os + 1);

        const int jA = os * 64 + fq8;
        const int jB = jA + 32;

        u16x8 vhA, vlA, vhB, vlB;
        {
            float4 r0a = *(const float4*)(rt + jA), r0b = *(const float4*)(rt + jA + 4);
            float4 r1a = *(const float4*)(rt + 512 + jA), r1b = *(const float4*)(rt + 512 + jA + 4);
            float4 r2a = *(const float4*)(rt + 1024 + jA), r2b = *(const float4*)(rt + 1024 + jA + 4);
            float e0[8] = {r0a.x, r0a.y, r0a.z, r0a.w, r0b.x, r0b.y, r0b.z, r0b.w};
            float e1[8] = {r1a.x, r1a.y, r1a.z, r1a.w, r1b.x, r1b.y, r1b.z, r1b.w};
            float e2[8] = {r2a.x, r2a.y, r2a.z, r2a.w, r2b.x, r2b.y, r2b.z, r2b.w};
            #pragma unroll
            for (int q = 0; q < 8; ++q) {
                unsigned av = ((q < 4 ? aA.x : aA.y) >> (8 * (q & 3))) & 255u;
                float sb = (av == 1u) ? (lf0 + e0[q])
                         : (av == 2u) ? (lf1 + e1[q]) : (lf2 + e2[q]);
                float sv = fmaxf(sb, 0.f) + 0.2f * fminf(sb, 0.f);
                float p = (av != 0u) ? __expf(sv) : 0.f;
                rsum += p;
                unsigned short hi = f2h(p);
                vhA[q] = hi;
                vlA[q] = f2h(p - h2f(hi));
            }
        }
        {
            float4 r0a = *(const float4*)(rt + jB), r0b = *(const float4*)(rt + jB + 4);
            float4 r1a = *(const float4*)(rt + 512 + jB), r1b = *(const float4*)(rt + 512 + jB + 4);
            float4 r2a = *(const float4*)(rt + 1024 + jB), r2b = *(const float4*)(rt + 1024 + jB + 4);
            float e0[8] = {r0a.x, r0a.y, r0a.z, r0a.w, r0b.x, r0b.y, r0b.z, r0b.w};
            float e1[8] = {r1a.x, r1a.y, r1a.z, r1a.w, r1b.x, r1b.y, r1b.z, r1b.w};
            float e2[8] = {r2a.x, r2a.y, r2a.z, r2a.w, r2b.x, r2b.y, r2b.z, r2b.w};
            #pragma unroll
            for (int q = 0; q < 8; ++q) {
                unsigned av = ((q < 4 ? aB.x : aB.y) >> (8 * (q & 3))) & 255u;
                float sb = (av == 1u) ? (lf0 + e0[q])
                         : (av == 2u) ? (lf1 + e1[q]) : (lf2 + e2[q]);
                float sv = fmaxf(sb, 0.f) + 0.2f * fminf(sb, 0.f);
                float p = (av != 0u) ? __expf(sv) : 0.f;
                rsum += p;
                unsigned short hi = f2h(p);
                vhB[q] = hi;
                vlB[q] = f2h(p - h2f(hi));
            }
        }
        if (os < 7) {
            aA = *(const uint2*)(arow + (os + 1) * 64 + fq8);
            aB = *(const uint2*)(arow + (os + 1) * 64 + fq8 + 32);
        }

        half8 ahA = *(half8*)&vhA, alA = *(half8*)&vlA;
        half8 ahB = *(half8*)&vhB, alB = *(half8*)&vlB;

        #pragma unroll
        for (int n = 0; n < 8; ++n) {
            half8 vA = *(half8*)(vb + (n * 2 + 0) * 512 + lane * 8);
            half8 vB = *(half8*)(vb + (n * 2 + 1) * 512 + lane * 8);
            acc[n] = __builtin_amdgcn_mfma_f32_16x16x32_f16(ahA, vA, acc[n], 0, 0, 0);
            acc[n] = __builtin_amdgcn_mfma_f32_16x16x32_f16(alA, vA, acc[n], 0, 0, 0);
            acc[n] = __builtin_amdgcn_mfma_f32_16x16x32_f16(ahB, vB, acc[n], 0, 0, 0);
            acc[n] = __builtin_amdgcn_mfma_f32_16x16x32_f16(alB, vB, acc[n], 0, 0, 0);
        }
        __syncthreads();
    }
#undef STAGE_V

    rsum += __shfl_xor(rsum, 16);
    rsum += __shfl_xor(rsum, 32);

    #pragma unroll
    for (int rr = 0; rr < 4; ++rr) {
        const int row = fq * 4 + rr;
        const float inv = 1.0f / __shfl(rsum, row);
        #pragma unroll
        for (int n = 0; n < 8; ++n) {
            out[(size_t)(b * 512 + i0 + row) * 1024 + h * 128 + n * 16 + fr] =
                fmaxf(acc[n][rr] * inv, 0.f);
        }
    }
}

// ---------------------------------------------------------------------------
extern "C" void kernel_launch(void* const* d_in, const int* in_sizes, int n_in,
                              void* d_out, int out_size, void* d_ws, size_t ws_size,
                              hipStream_t stream) {
    const float* x   = (const float*)d_in[0];
    const int*   adj = (const int*)d_in[1];
    const float* nm  = (const float*)d_in[2];
    const float* W   = (const float*)d_in[3];
    const float* a1  = (const float*)d_in[4];
    const float* a2  = (const float*)d_in[5];
    float* out = (float*)d_out;
    char* wsb = (char*)d_ws;

    unsigned short* Bf   = (unsigned short*)(wsb);
    float*          LR   = (float*)(wsb + 21495808);
    unsigned short* Vt   = (unsigned short*)(wsb + 23068672);
    unsigned char*  adjB = (unsigned char*)(wsb + 39845888);

    hipLaunchKernelGGL(adjb_kernel, dim3(1024), dim3(256), 0, stream, adj, adjB);
    hipLaunchKernelGGL(pack_all, dim3(592), dim3(256), 0, stream, W, a1, a2, Bf);
    hipLaunchKernelGGL(mgemm, dim3(576), dim3(256), 0, stream, x, Bf, nm, Vt, LR);
    hipLaunchKernelGGL(attn_kernel, dim3(1024), dim3(256), 0, stream, Vt, LR, adjB, out);
}

// Round 22
// 109.732 us; speedup vs baseline: 1.3716x; 1.0651x over previous
//
#include <hip/hip_runtime.h>

typedef __attribute__((ext_vector_type(8))) _Float16 half8;
typedef __attribute__((ext_vector_type(8))) unsigned short u16x8;
typedef __attribute__((ext_vector_type(4))) unsigned short u16x4;
typedef __attribute__((ext_vector_type(4))) float f32x4;

#define NEGV (-1e30f)

// ---------------------------------------------------------------------------
// Workspace layout (bytes):
//  Bf  : [1152][1024] fp16 @ 0          (2,359,296)   packed B (single fp16)
//  LR  : [48][8192]  f32   @ 21495808   (1,572,864)
//  Vt  : [8][16][128][512] fp16 @ 23068672 (16,777,216)  written by mgemm
//  adjB: [16][512][512] u8 @ 39845888   (4,194,304)
//  total 44,040,192 B
// ---------------------------------------------------------------------------

__device__ __forceinline__ unsigned short f2h(float f) {
    union { _Float16 h; unsigned short u; } c;
    c.h = (_Float16)f;
    return c.u;
}
__device__ __forceinline__ float h2f(unsigned short u) {
    union { _Float16 h; unsigned short u; } c;
    c.u = u;
    return (float)c.h;
}

// ---------------------------------------------------------------------------
// Kernel 1: fused prep (adj->bytes + pack tr/wa/zero).  grid 1616.
// ---------------------------------------------------------------------------
__global__ __launch_bounds__(256) void prep_kernel(const int* __restrict__ adj,
                                                   const float* __restrict__ W,
                                                   const float* __restrict__ a1,
                                                   const float* __restrict__ a2,
                                                   unsigned short* __restrict__ Bf,
                                                   unsigned char* __restrict__ adjB) {
    __shared__ float tile[64 * 133];
    const int bid = blockIdx.x;
    const int tid = threadIdx.x;

    if (bid < 1024) {
        const int idx = bid * 256 + tid;
        const int4* s = (const int4*)(adj + (size_t)idx * 16);
        int4 v0 = s[0], v1 = s[1], v2 = s[2], v3 = s[3];
        union { unsigned char c[16]; int4 v; } o;
        o.c[0] = (unsigned char)v0.x; o.c[1] = (unsigned char)v0.y;
        o.c[2] = (unsigned char)v0.z; o.c[3] = (unsigned char)v0.w;
        o.c[4] = (unsigned char)v1.x; o.c[5] = (unsigned char)v1.y;
        o.c[6] = (unsigned char)v1.z; o.c[7] = (unsigned char)v1.w;
        o.c[8] = (unsigned char)v2.x; o.c[9] = (unsigned char)v2.y;
        o.c[10] = (unsigned char)v2.z; o.c[11] = (unsigned char)v2.w;
        o.c[12] = (unsigned char)v3.x; o.c[13] = (unsigned char)v3.y;
        o.c[14] = (unsigned char)v3.z; o.c[15] = (unsigned char)v3.w;
        *(int4*)(adjB + (size_t)idx * 16) = o.v;
    } else if (bid < 1152) {
        const int pb = bid - 1024;
        const int kt = pb & 15, h = pb >> 4;
        const int k0 = kt * 64;
        const float* wsrc = W + ((size_t)((h * 3 + 2) * 1024) + k0) * 128;

        #pragma unroll
        for (int rep = 0; rep < 8; ++rep) {
            int idx = rep * 256 + tid;
            int k = idx >> 5, dc = (idx & 31) * 4;
            float4 v = *(const float4*)(wsrc + (size_t)k * 128 + dc);
            tile[k * 133 + dc + 0] = v.x;
            tile[k * 133 + dc + 1] = v.y;
            tile[k * 133 + dc + 2] = v.z;
            tile[k * 133 + dc + 3] = v.w;
        }
        __syncthreads();
        #pragma unroll
        for (int rep = 0; rep < 4; ++rep) {
            int idx = rep * 256 + tid;
            int d = idx >> 3, kc = (idx & 7) * 8;
            u16x8 vh;
            #pragma unroll
            for (int q = 0; q < 8; ++q) vh[q] = f2h(tile[(kc + q) * 133 + d]);
            *(u16x8*)(Bf + (size_t)(h * 128 + d) * 1024 + k0 + kc) = vh;
        }
    } else if (bid < 1536) {
        const int pb = bid - 1152;
        const int kt = pb & 15, ht = pb >> 4;
        const int h = ht & 7, t = ht >> 3;
        const int k0 = kt * 64;
        const float* wsrc = W + ((size_t)((h * 3 + t) * 1024) + k0) * 128;

        #pragma unroll
        for (int rep = 0; rep < 8; ++rep) {
            int idx = rep * 256 + tid;
            int k = idx >> 5, dc = (idx & 31) * 4;
            float4 v = *(const float4*)(wsrc + (size_t)k * 128 + dc);
            tile[k * 133 + dc + 0] = v.x;
            tile[k * 133 + dc + 1] = v.y;
            tile[k * 133 + dc + 2] = v.z;
            tile[k * 133 + dc + 3] = v.w;
        }
        __syncthreads();
        if (tid < 128) {
            const int k = tid & 63, s = tid >> 6;
            const float* ar = (s ? a2 : a1) + (h * 3 + t) * 128;
            float acc = 0.f;
            #pragma unroll 4
            for (int d = 0; d < 128; ++d) acc += tile[k * 133 + d] * ar[d];
            Bf[(size_t)(1024 + s * 24 + t * 8 + h) * 1024 + k0 + k] = f2h(acc);
        }
    } else {
        const int n = 1072 + (bid - 1536);
        *(unsigned long long*)(Bf + (size_t)n * 1024 + tid * 4) = 0ull;
    }
}

// ---------------------------------------------------------------------------
// Kernel 2: fp16 MFMA GEMM — r21-exact (verified 67us): dbuf, single barrier,
//   X hi/lo fp16 split (precision-critical, kept), B single fp16.
// ---------------------------------------------------------------------------
__global__ __launch_bounds__(256, 3) void mgemm(const float* __restrict__ X,
                                                const unsigned short* __restrict__ Bf,
                                                const float* __restrict__ nm,
                                                unsigned short* __restrict__ Vt,
                                                float* __restrict__ LR) {
    __shared__ unsigned short Ah[2][128 * 32];
    __shared__ unsigned short Al[2][128 * 32];
    __shared__ unsigned short Bfs[2][128 * 32];

    const int bid = blockIdx.x;                 // 0..575
    const int swz = (bid & 7) * 72 + (bid >> 3); // XCD-aware, bijective
    const int nt = swz % 9, mt = swz / 9;
    const int n0 = nt * 128, m0 = mt * 128;

    const int tid = threadIdx.x;
    const int lane = tid & 63, w = tid >> 6;
    const int wr = w >> 1, wc = w & 1;
    const int fr = lane & 15, fq = lane >> 4;

    f32x4 acc[4][4];
    #pragma unroll
    for (int m = 0; m < 4; ++m)
        #pragma unroll
        for (int n = 0; n < 4; ++n) acc[m][n] = (f32x4){0.f, 0.f, 0.f, 0.f};

    const int arow = tid >> 1, ahalf = tid & 1;
    const float* xs = X + (size_t)(m0 + arow) * 1024 + ahalf * 16;
    const int aoff = arow * 32 + ahalf * 16;

#define GLDB(kk, buf) do {                                                        \
        _Pragma("unroll")                                                          \
        for (int q_ = 0; q_ < 2; ++q_) {                                           \
            const int s_ = q_ * 256 + tid;                                         \
            const int brow_ = s_ >> 2, bkb_ = s_ & 3;                              \
            const unsigned short* g_ = Bf + (size_t)(n0 + brow_) * 1024 + (kk) + bkb_ * 8; \
            unsigned short* d_ = &Bfs[buf][(q_ * 256 + w * 64) * 8];               \
            __builtin_amdgcn_global_load_lds(                                      \
                (const __attribute__((address_space(1))) void*)g_,                 \
                (__attribute__((address_space(3))) void*)d_, 16, 0, 0);            \
        }                                                                          \
    } while (0)

#define CONVA(xa_, xb_, buf) do {                                                 \
        float xf_[8] = {(xa_).x, (xa_).y, (xa_).z, (xa_).w,                        \
                        (xb_).x, (xb_).y, (xb_).z, (xb_).w};                       \
        u16x8 vh_, vl_;                                                            \
        _Pragma("unroll")                                                          \
        for (int i_ = 0; i_ < 8; ++i_) {                                           \
            unsigned short hi_ = f2h(xf_[i_]);                                     \
            vh_[i_] = hi_;                                                         \
            vl_[i_] = f2h(xf_[i_] - h2f(hi_));                                     \
        }                                                                          \
        *(u16x8*)(&Ah[buf][aoff]) = vh_;                                           \
        *(u16x8*)(&Al[buf][aoff]) = vl_;                                           \
    } while (0)

#define CONVA2(xa_, xb_, buf) do {                                                \
        float xf_[8] = {(xa_).x, (xa_).y, (xa_).z, (xa_).w,                        \
                        (xb_).x, (xb_).y, (xb_).z, (xb_).w};                       \
        u16x8 vh_, vl_;                                                            \
        _Pragma("unroll")                                                          \
        for (int i_ = 0; i_ < 8; ++i_) {                                           \
            unsigned short hi_ = f2h(xf_[i_]);                                     \
            vh_[i_] = hi_;                                                         \
            vl_[i_] = f2h(xf_[i_] - h2f(hi_));                                     \
        }                                                                          \
        *(u16x8*)(&Ah[buf][aoff + 8]) = vh_;                                       \
        *(u16x8*)(&Al[buf][aoff + 8]) = vl_;                                       \
    } while (0)

    // ---- prologue: stage step 0 into buf 0
    GLDB(0, 0);
    {
        float4 xa = *(const float4*)(xs);
        float4 xb = *(const float4*)(xs + 4);
        float4 xc = *(const float4*)(xs + 8);
        float4 xd = *(const float4*)(xs + 12);
        CONVA(xa, xb, 0);
        CONVA2(xc, xd, 0);
    }
    __syncthreads();

    for (int k0 = 0; k0 < 1024; k0 += 32) {
        const int cur = (k0 >> 5) & 1;
        const int nxt = cur ^ 1;
        const bool more = (k0 < 992);

        float4 xa, xb, xc, xd;
        if (more) {
            GLDB(k0 + 32, nxt);
            xa = *(const float4*)(xs + k0 + 32);
            xb = *(const float4*)(xs + k0 + 36);
            xc = *(const float4*)(xs + k0 + 40);
            xd = *(const float4*)(xs + k0 + 44);
        }

        half8 amh[4], bn[4];
        #pragma unroll
        for (int m = 0; m < 4; ++m)
            amh[m] = *(half8*)(&Ah[cur][(wr * 64 + m * 16 + fr) * 32 + fq * 8]);
        #pragma unroll
        for (int n = 0; n < 4; ++n)
            bn[n] = *(half8*)(&Bfs[cur][(wc * 64 + n * 16 + fr) * 32 + fq * 8]);
        #pragma unroll
        for (int m = 0; m < 4; ++m)
            #pragma unroll
            for (int n = 0; n < 4; ++n)
                acc[m][n] = __builtin_amdgcn_mfma_f32_16x16x32_f16(amh[m], bn[n], acc[m][n], 0, 0, 0);

        half8 aml[4];
        #pragma unroll
        for (int m = 0; m < 4; ++m)
            aml[m] = *(half8*)(&Al[cur][(wr * 64 + m * 16 + fr) * 32 + fq * 8]);
        #pragma unroll
        for (int m = 0; m < 4; ++m)
            #pragma unroll
            for (int n = 0; n < 4; ++n)
                acc[m][n] = __builtin_amdgcn_mfma_f32_16x16x32_f16(aml[m], bn[n], acc[m][n], 0, 0, 0);

        if (more) {
            CONVA(xa, xb, nxt);
            CONVA2(xc, xd, nxt);
        }

        __syncthreads();
    }
#undef GLDB
#undef CONVA
#undef CONVA2

    // ---- epilogue: C/D layout col=lane&15, row=(lane>>4)*4+reg
    if (nt < 8) {
        const int b_ = (mt * 128) >> 9;
        const int jb0 = (mt & 3) * 128;
        unsigned short* vtw = Vt + (size_t)(nt * 16 + b_) * 128 * 512;
        #pragma unroll
        for (int m = 0; m < 4; ++m) {
            const int jb = jb0 + wr * 64 + m * 16 + fq * 4;
            float mk[4];
            #pragma unroll
            for (int r = 0; r < 4; ++r)
                mk[r] = nm[m0 + wr * 64 + m * 16 + fq * 4 + r];
            #pragma unroll
            for (int n = 0; n < 4; ++n) {
                const int d = wc * 64 + n * 16 + fr;
                u16x4 pk;
                #pragma unroll
                for (int r = 0; r < 4; ++r) pk[r] = f2h(acc[m][n][r] * mk[r]);
                *(u16x4*)(vtw + (size_t)d * 512 + jb) = pk;
            }
        }
    } else {
        #pragma unroll
        for (int m = 0; m < 4; ++m) {
            #pragma unroll
            for (int r = 0; r < 4; ++r) {
                const int R = m0 + wr * 64 + m * 16 + fq * 4 + r;
                #pragma unroll
                for (int n = 0; n < 4; ++n) {
                    const int c = wc * 64 + n * 16 + fr;
                    if (c < 48) LR[(size_t)c * 8192 + R] = acc[m][n][r];
                }
            }
        }
    }
}

// ---------------------------------------------------------------------------
// Kernel 4: fused attn — r20 schedule, P single fp16 (lo-split dropped:
//   PV error contribution ~1e-5, invisible vs 9.77e-4 absmax).
//   16 MFMA/step (was 32); score-phase conversion halved.
// ---------------------------------------------------------------------------
__global__ __launch_bounds__(256, 4) void attn_kernel(const unsigned short* __restrict__ Vt,
                                                      const float* __restrict__ LR,
                                                      const unsigned char* __restrict__ adjB,
                                                      float* __restrict__ out) {
    __shared__ __align__(16) unsigned short Vb[2][16 * 512];
    __shared__ __align__(16) float rt[3 * 512];

    const int bid = blockIdx.x;
    const int itg = bid >> 7, hb = bid & 127, h = hb >> 4, b = hb & 15;
    const int tid = threadIdx.x, w = tid >> 6, lane = tid & 63;
    const int fr = lane & 15, fq = lane >> 4;
    const int i0 = (itg * 4 + w) * 16;
    const int fq8 = fq * 8;

    for (int idx = tid; idx < 1536; idx += 256) {
        int t = idx >> 9, j = idx & 511;
        rt[idx] = LR[(size_t)(24 + t * 8 + h) * 8192 + b * 512 + j];
    }
    const float lf0 = LR[(size_t)(h) * 8192 + b * 512 + i0 + fr];
    const float lf1 = LR[(size_t)(8 + h) * 8192 + b * 512 + i0 + fr];
    const float lf2 = LR[(size_t)(16 + h) * 8192 + b * 512 + i0 + fr];
    const unsigned char* arow = adjB + (size_t)(b * 512 + i0 + fr) * 512;
    const unsigned short* vt = Vt + (size_t)(h * 16 + b) * 128 * 512;

#define STAGE_V(bufp, os_) do {                                                   \
        _Pragma("unroll")                                                          \
        for (int q_ = 0; q_ < 4; ++q_) {                                           \
            const int nh_ = q_ * 4 + w;                                            \
            const unsigned short* src_ = vt + (size_t)((nh_ >> 1) * 16 + fr) * 512 \
                                          + (os_) * 64 + (nh_ & 1) * 32 + fq8;     \
            unsigned short* dst_ = (bufp) + nh_ * 512;                             \
            __builtin_amdgcn_global_load_lds(                                      \
                (const __attribute__((address_space(1))) void*)src_,               \
                (__attribute__((address_space(3))) void*)dst_, 16, 0, 0);          \
        }                                                                          \
    } while (0)

    STAGE_V(&Vb[0][0], 0);
    uint2 aA = *(const uint2*)(arow + fq8);
    uint2 aB = *(const uint2*)(arow + fq8 + 32);

    f32x4 acc[8];
    #pragma unroll
    for (int n = 0; n < 8; ++n) acc[n] = (f32x4){0.f, 0.f, 0.f, 0.f};
    float rsum = 0.f;

    __syncthreads();

    #pragma unroll 1
    for (int os = 0; os < 8; ++os) {
        unsigned short* vb = &Vb[os & 1][0];
        if (os < 7) STAGE_V(&Vb[(os & 1) ^ 1][0], os + 1);

        const int jA = os * 64 + fq8;
        const int jB = jA + 32;

        u16x8 vhA, vhB;
        {
            float4 r0a = *(const float4*)(rt + jA), r0b = *(const float4*)(rt + jA + 4);
            float4 r1a = *(const float4*)(rt + 512 + jA), r1b = *(const float4*)(rt + 512 + jA + 4);
            float4 r2a = *(const float4*)(rt + 1024 + jA), r2b = *(const float4*)(rt + 1024 + jA + 4);
            float e0[8] = {r0a.x, r0a.y, r0a.z, r0a.w, r0b.x, r0b.y, r0b.z, r0b.w};
            float e1[8] = {r1a.x, r1a.y, r1a.z, r1a.w, r1b.x, r1b.y, r1b.z, r1b.w};
            float e2[8] = {r2a.x, r2a.y, r2a.z, r2a.w, r2b.x, r2b.y, r2b.z, r2b.w};
            #pragma unroll
            for (int q = 0; q < 8; ++q) {
                unsigned av = ((q < 4 ? aA.x : aA.y) >> (8 * (q & 3))) & 255u;
                float sb = (av == 1u) ? (lf0 + e0[q])
                         : (av == 2u) ? (lf1 + e1[q]) : (lf2 + e2[q]);
                float sv = fmaxf(sb, 0.f) + 0.2f * fminf(sb, 0.f);
                float p = (av != 0u) ? __expf(sv) : 0.f;
                rsum += p;
                vhA[q] = f2h(p);
            }
        }
        {
            float4 r0a = *(const float4*)(rt + jB), r0b = *(const float4*)(rt + jB + 4);
            float4 r1a = *(const float4*)(rt + 512 + jB), r1b = *(const float4*)(rt + 512 + jB + 4);
            float4 r2a = *(const float4*)(rt + 1024 + jB), r2b = *(const float4*)(rt + 1024 + jB + 4);
            float e0[8] = {r0a.x, r0a.y, r0a.z, r0a.w, r0b.x, r0b.y, r0b.z, r0b.w};
            float e1[8] = {r1a.x, r1a.y, r1a.z, r1a.w, r1b.x, r1b.y, r1b.z, r1b.w};
            float e2[8] = {r2a.x, r2a.y, r2a.z, r2a.w, r2b.x, r2b.y, r2b.z, r2b.w};
            #pragma unroll
            for (int q = 0; q < 8; ++q) {
                unsigned av = ((q < 4 ? aB.x : aB.y) >> (8 * (q & 3))) & 255u;
                float sb = (av == 1u) ? (lf0 + e0[q])
                         : (av == 2u) ? (lf1 + e1[q]) : (lf2 + e2[q]);
                float sv = fmaxf(sb, 0.f) + 0.2f * fminf(sb, 0.f);
                float p = (av != 0u) ? __expf(sv) : 0.f;
                rsum += p;
                vhB[q] = f2h(p);
            }
        }
        if (os < 7) {
            aA = *(const uint2*)(arow + (os + 1) * 64 + fq8);
            aB = *(const uint2*)(arow + (os + 1) * 64 + fq8 + 32);
        }

        half8 ahA = *(half8*)&vhA, ahB = *(half8*)&vhB;

        #pragma unroll
        for (int n = 0; n < 8; ++n) {
            half8 vA = *(half8*)(vb + (n * 2 + 0) * 512 + lane * 8);
            half8 vB = *(half8*)(vb + (n * 2 + 1) * 512 + lane * 8);
            acc[n] = __builtin_amdgcn_mfma_f32_16x16x32_f16(ahA, vA, acc[n], 0, 0, 0);
            acc[n] = __builtin_amdgcn_mfma_f32_16x16x32_f16(ahB, vB, acc[n], 0, 0, 0);
        }
        __syncthreads();
    }
#undef STAGE_V

    rsum += __shfl_xor(rsum, 16);
    rsum += __shfl_xor(rsum, 32);

    #pragma unroll
    for (int rr = 0; rr < 4; ++rr) {
        const int row = fq * 4 + rr;
        const float inv = 1.0f / __shfl(rsum, row);
        #pragma unroll
        for (int n = 0; n < 8; ++n) {
            out[(size_t)(b * 512 + i0 + row) * 1024 + h * 128 + n * 16 + fr] =
                fmaxf(acc[n][rr] * inv, 0.f);
        }
    }
}

// ---------------------------------------------------------------------------
extern "C" void kernel_launch(void* const* d_in, const int* in_sizes, int n_in,
                              void* d_out, int out_size, void* d_ws, size_t ws_size,
                              hipStream_t stream) {
    const float* x   = (const float*)d_in[0];
    const int*   adj = (const int*)d_in[1];
    const float* nm  = (const float*)d_in[2];
    const float* W   = (const float*)d_in[3];
    const float* a1  = (const float*)d_in[4];
    const float* a2  = (const float*)d_in[5];
    float* out = (float*)d_out;
    char* wsb = (char*)d_ws;

    unsigned short* Bf   = (unsigned short*)(wsb);
    float*          LR   = (float*)(wsb + 21495808);
    unsigned short* Vt   = (unsigned short*)(wsb + 23068672);
    unsigned char*  adjB = (unsigned char*)(wsb + 39845888);

    hipLaunchKernelGGL(prep_kernel, dim3(1616), dim3(256), 0, stream, adj, W, a1, a2, Bf, adjB);
    hipLaunchKernelGGL(mgemm, dim3(576), dim3(256), 0, stream, x, Bf, nm, Vt, LR);
    hipLaunchKernelGGL(attn_kernel, dim3(1024), dim3(256), 0, stream, Vt, LR, adjB, out);
}

// Round 23
// 108.372 us; speedup vs baseline: 1.3888x; 1.0125x over previous
//
#include <hip/hip_runtime.h>

typedef __attribute__((ext_vector_type(8))) _Float16 half8;
typedef __attribute__((ext_vector_type(8))) unsigned short u16x8;
typedef __attribute__((ext_vector_type(4))) unsigned short u16x4;
typedef __attribute__((ext_vector_type(4))) float f32x4;

#define NEGV (-1e30f)

// ---------------------------------------------------------------------------
// Workspace layout (bytes):
//  Bf  : [1152][1024] fp16 @ 0          (2,359,296)   packed B (single fp16)
//  LR  : [48][8192]  f32   @ 21495808   (1,572,864)
//  Vt  : [8][16][128][512] fp16 @ 23068672 (16,777,216)  written by mgemm
//  adjB: [16][512][512] u8 @ 39845888   (4,194,304)
//  total 44,040,192 B
// ---------------------------------------------------------------------------

__device__ __forceinline__ unsigned short f2h(float f) {
    union { _Float16 h; unsigned short u; } c;
    c.h = (_Float16)f;
    return c.u;
}
__device__ __forceinline__ float h2f(unsigned short u) {
    union { _Float16 h; unsigned short u; } c;
    c.u = u;
    return (float)c.h;
}

// ---------------------------------------------------------------------------
// Kernel 1: fused prep (adj->bytes + pack tr/wa/zero).  grid 1616. [verified]
// ---------------------------------------------------------------------------
__global__ __launch_bounds__(256) void prep_kernel(const int* __restrict__ adj,
                                                   const float* __restrict__ W,
                                                   const float* __restrict__ a1,
                                                   const float* __restrict__ a2,
                                                   unsigned short* __restrict__ Bf,
                                                   unsigned char* __restrict__ adjB) {
    __shared__ float tile[64 * 133];
    const int bid = blockIdx.x;
    const int tid = threadIdx.x;

    if (bid < 1024) {
        const int idx = bid * 256 + tid;
        const int4* s = (const int4*)(adj + (size_t)idx * 16);
        int4 v0 = s[0], v1 = s[1], v2 = s[2], v3 = s[3];
        union { unsigned char c[16]; int4 v; } o;
        o.c[0] = (unsigned char)v0.x; o.c[1] = (unsigned char)v0.y;
        o.c[2] = (unsigned char)v0.z; o.c[3] = (unsigned char)v0.w;
        o.c[4] = (unsigned char)v1.x; o.c[5] = (unsigned char)v1.y;
        o.c[6] = (unsigned char)v1.z; o.c[7] = (unsigned char)v1.w;
        o.c[8] = (unsigned char)v2.x; o.c[9] = (unsigned char)v2.y;
        o.c[10] = (unsigned char)v2.z; o.c[11] = (unsigned char)v2.w;
        o.c[12] = (unsigned char)v3.x; o.c[13] = (unsigned char)v3.y;
        o.c[14] = (unsigned char)v3.z; o.c[15] = (unsigned char)v3.w;
        *(int4*)(adjB + (size_t)idx * 16) = o.v;
    } else if (bid < 1152) {
        const int pb = bid - 1024;
        const int kt = pb & 15, h = pb >> 4;
        const int k0 = kt * 64;
        const float* wsrc = W + ((size_t)((h * 3 + 2) * 1024) + k0) * 128;

        #pragma unroll
        for (int rep = 0; rep < 8; ++rep) {
            int idx = rep * 256 + tid;
            int k = idx >> 5, dc = (idx & 31) * 4;
            float4 v = *(const float4*)(wsrc + (size_t)k * 128 + dc);
            tile[k * 133 + dc + 0] = v.x;
            tile[k * 133 + dc + 1] = v.y;
            tile[k * 133 + dc + 2] = v.z;
            tile[k * 133 + dc + 3] = v.w;
        }
        __syncthreads();
        #pragma unroll
        for (int rep = 0; rep < 4; ++rep) {
            int idx = rep * 256 + tid;
            int d = idx >> 3, kc = (idx & 7) * 8;
            u16x8 vh;
            #pragma unroll
            for (int q = 0; q < 8; ++q) vh[q] = f2h(tile[(kc + q) * 133 + d]);
            *(u16x8*)(Bf + (size_t)(h * 128 + d) * 1024 + k0 + kc) = vh;
        }
    } else if (bid < 1536) {
        const int pb = bid - 1152;
        const int kt = pb & 15, ht = pb >> 4;
        const int h = ht & 7, t = ht >> 3;
        const int k0 = kt * 64;
        const float* wsrc = W + ((size_t)((h * 3 + t) * 1024) + k0) * 128;

        #pragma unroll
        for (int rep = 0; rep < 8; ++rep) {
            int idx = rep * 256 + tid;
            int k = idx >> 5, dc = (idx & 31) * 4;
            float4 v = *(const float4*)(wsrc + (size_t)k * 128 + dc);
            tile[k * 133 + dc + 0] = v.x;
            tile[k * 133 + dc + 1] = v.y;
            tile[k * 133 + dc + 2] = v.z;
            tile[k * 133 + dc + 3] = v.w;
        }
        __syncthreads();
        if (tid < 128) {
            const int k = tid & 63, s = tid >> 6;
            const float* ar = (s ? a2 : a1) + (h * 3 + t) * 128;
            float acc = 0.f;
            #pragma unroll 4
            for (int d = 0; d < 128; ++d) acc += tile[k * 133 + d] * ar[d];
            Bf[(size_t)(1024 + s * 24 + t * 8 + h) * 1024 + k0 + k] = f2h(acc);
        }
    } else {
        const int n = 1072 + (bid - 1536);
        *(unsigned long long*)(Bf + (size_t)n * 1024 + tid * 4) = 0ull;
    }
}

// ---------------------------------------------------------------------------
// Kernel 2: fp16 MFMA GEMM — r21 dbuf schedule, A SINGLE fp16 (lo-split
//   dropped: h-error averaged through attention coefs, absmax-invariant
//   empirically across 3 prior precision changes). 16 MFMA/step, LDS 32KB.
// ---------------------------------------------------------------------------
__global__ __launch_bounds__(256, 3) void mgemm(const float* __restrict__ X,
                                                const unsigned short* __restrict__ Bf,
                                                const float* __restrict__ nm,
                                                unsigned short* __restrict__ Vt,
                                                float* __restrict__ LR) {
    __shared__ unsigned short Ah[2][128 * 32];
    __shared__ unsigned short Bfs[2][128 * 32];

    const int bid = blockIdx.x;                 // 0..575
    const int swz = (bid & 7) * 72 + (bid >> 3); // XCD-aware, bijective
    const int nt = swz % 9, mt = swz / 9;
    const int n0 = nt * 128, m0 = mt * 128;

    const int tid = threadIdx.x;
    const int lane = tid & 63, w = tid >> 6;
    const int wr = w >> 1, wc = w & 1;
    const int fr = lane & 15, fq = lane >> 4;

    f32x4 acc[4][4];
    #pragma unroll
    for (int m = 0; m < 4; ++m)
        #pragma unroll
        for (int n = 0; n < 4; ++n) acc[m][n] = (f32x4){0.f, 0.f, 0.f, 0.f};

    const int arow = tid >> 1, ahalf = tid & 1;
    const float* xs = X + (size_t)(m0 + arow) * 1024 + ahalf * 16;
    const int aoff = arow * 32 + ahalf * 16;

#define GLDB(kk, buf) do {                                                        \
        _Pragma("unroll")                                                          \
        for (int q_ = 0; q_ < 2; ++q_) {                                           \
            const int s_ = q_ * 256 + tid;                                         \
            const int brow_ = s_ >> 2, bkb_ = s_ & 3;                              \
            const unsigned short* g_ = Bf + (size_t)(n0 + brow_) * 1024 + (kk) + bkb_ * 8; \
            unsigned short* d_ = &Bfs[buf][(q_ * 256 + w * 64) * 8];               \
            __builtin_amdgcn_global_load_lds(                                      \
                (const __attribute__((address_space(1))) void*)g_,                 \
                (__attribute__((address_space(3))) void*)d_, 16, 0, 0);            \
        }                                                                          \
    } while (0)

#define CONVA(xa_, xb_, xc_, xd_, buf) do {                                       \
        float xf_[16] = {(xa_).x, (xa_).y, (xa_).z, (xa_).w,                       \
                         (xb_).x, (xb_).y, (xb_).z, (xb_).w,                       \
                         (xc_).x, (xc_).y, (xc_).z, (xc_).w,                       \
                         (xd_).x, (xd_).y, (xd_).z, (xd_).w};                      \
        u16x8 v0_, v1_;                                                            \
        _Pragma("unroll")                                                          \
        for (int i_ = 0; i_ < 8; ++i_) v0_[i_] = f2h(xf_[i_]);                     \
        _Pragma("unroll")                                                          \
        for (int i_ = 0; i_ < 8; ++i_) v1_[i_] = f2h(xf_[8 + i_]);                 \
        *(u16x8*)(&Ah[buf][aoff]) = v0_;                                           \
        *(u16x8*)(&Ah[buf][aoff + 8]) = v1_;                                       \
    } while (0)

    // ---- prologue: stage step 0 into buf 0
    GLDB(0, 0);
    {
        float4 xa = *(const float4*)(xs);
        float4 xb = *(const float4*)(xs + 4);
        float4 xc = *(const float4*)(xs + 8);
        float4 xd = *(const float4*)(xs + 12);
        CONVA(xa, xb, xc, xd, 0);
    }
    __syncthreads();

    for (int k0 = 0; k0 < 1024; k0 += 32) {
        const int cur = (k0 >> 5) & 1;
        const int nxt = cur ^ 1;
        const bool more = (k0 < 992);

        // ---- issue next-step loads FIRST
        float4 xa, xb, xc, xd;
        if (more) {
            GLDB(k0 + 32, nxt);
            xa = *(const float4*)(xs + k0 + 32);
            xb = *(const float4*)(xs + k0 + 36);
            xc = *(const float4*)(xs + k0 + 40);
            xd = *(const float4*)(xs + k0 + 44);
        }

        // ---- compute current step: 8 frag reads + 16 MFMA
        half8 am[4], bn[4];
        #pragma unroll
        for (int m = 0; m < 4; ++m)
            am[m] = *(half8*)(&Ah[cur][(wr * 64 + m * 16 + fr) * 32 + fq * 8]);
        #pragma unroll
        for (int n = 0; n < 4; ++n)
            bn[n] = *(half8*)(&Bfs[cur][(wc * 64 + n * 16 + fr) * 32 + fq * 8]);
        #pragma unroll
        for (int m = 0; m < 4; ++m)
            #pragma unroll
            for (int n = 0; n < 4; ++n)
                acc[m][n] = __builtin_amdgcn_mfma_f32_16x16x32_f16(am[m], bn[n], acc[m][n], 0, 0, 0);

        // ---- convert + write next A (X regs arrived during compute)
        if (more) {
            CONVA(xa, xb, xc, xd, nxt);
        }

        __syncthreads();   // single barrier per step
    }
#undef GLDB
#undef CONVA

    // ---- epilogue: C/D layout col=lane&15, row=(lane>>4)*4+reg
    if (nt < 8) {
        const int b_ = (mt * 128) >> 9;
        const int jb0 = (mt & 3) * 128;
        unsigned short* vtw = Vt + (size_t)(nt * 16 + b_) * 128 * 512;
        #pragma unroll
        for (int m = 0; m < 4; ++m) {
            const int jb = jb0 + wr * 64 + m * 16 + fq * 4;
            float mk[4];
            #pragma unroll
            for (int r = 0; r < 4; ++r)
                mk[r] = nm[m0 + wr * 64 + m * 16 + fq * 4 + r];
            #pragma unroll
            for (int n = 0; n < 4; ++n) {
                const int d = wc * 64 + n * 16 + fr;
                u16x4 pk;
                #pragma unroll
                for (int r = 0; r < 4; ++r) pk[r] = f2h(acc[m][n][r] * mk[r]);
                *(u16x4*)(vtw + (size_t)d * 512 + jb) = pk;
            }
        }
    } else {
        #pragma unroll
        for (int m = 0; m < 4; ++m) {
            #pragma unroll
            for (int r = 0; r < 4; ++r) {
                const int R = m0 + wr * 64 + m * 16 + fq * 4 + r;
                #pragma unroll
                for (int n = 0; n < 4; ++n) {
                    const int c = wc * 64 + n * 16 + fr;
                    if (c < 48) LR[(size_t)c * 8192 + R] = acc[m][n][r];
                }
            }
        }
    }
}

// ---------------------------------------------------------------------------
// Kernel 4: fused attn — r22-exact (verified): P single fp16, 16 MFMA/step.
// ---------------------------------------------------------------------------
__global__ __launch_bounds__(256, 4) void attn_kernel(const unsigned short* __restrict__ Vt,
                                                      const float* __restrict__ LR,
                                                      const unsigned char* __restrict__ adjB,
                                                      float* __restrict__ out) {
    __shared__ __align__(16) unsigned short Vb[2][16 * 512];
    __shared__ __align__(16) float rt[3 * 512];

    const int bid = blockIdx.x;
    const int itg = bid >> 7, hb = bid & 127, h = hb >> 4, b = hb & 15;
    const int tid = threadIdx.x, w = tid >> 6, lane = tid & 63;
    const int fr = lane & 15, fq = lane >> 4;
    const int i0 = (itg * 4 + w) * 16;
    const int fq8 = fq * 8;

    for (int idx = tid; idx < 1536; idx += 256) {
        int t = idx >> 9, j = idx & 511;
        rt[idx] = LR[(size_t)(24 + t * 8 + h) * 8192 + b * 512 + j];
    }
    const float lf0 = LR[(size_t)(h) * 8192 + b * 512 + i0 + fr];
    const float lf1 = LR[(size_t)(8 + h) * 8192 + b * 512 + i0 + fr];
    const float lf2 = LR[(size_t)(16 + h) * 8192 + b * 512 + i0 + fr];
    const unsigned char* arow = adjB + (size_t)(b * 512 + i0 + fr) * 512;
    const unsigned short* vt = Vt + (size_t)(h * 16 + b) * 128 * 512;

#define STAGE_V(bufp, os_) do {                                                   \
        _Pragma("unroll")                                                          \
        for (int q_ = 0; q_ < 4; ++q_) {                                           \
            const int nh_ = q_ * 4 + w;                                            \
            const unsigned short* src_ = vt + (size_t)((nh_ >> 1) * 16 + fr) * 512 \
                                          + (os_) * 64 + (nh_ & 1) * 32 + fq8;     \
            unsigned short* dst_ = (bufp) + nh_ * 512;                             \
            __builtin_amdgcn_global_load_lds(                                      \
                (const __attribute__((address_space(1))) void*)src_,               \
                (__attribute__((address_space(3))) void*)dst_, 16, 0, 0);          \
        }                                                                          \
    } while (0)

    STAGE_V(&Vb[0][0], 0);
    uint2 aA = *(const uint2*)(arow + fq8);
    uint2 aB = *(const uint2*)(arow + fq8 + 32);

    f32x4 acc[8];
    #pragma unroll
    for (int n = 0; n < 8; ++n) acc[n] = (f32x4){0.f, 0.f, 0.f, 0.f};
    float rsum = 0.f;

    __syncthreads();

    #pragma unroll 1
    for (int os = 0; os < 8; ++os) {
        unsigned short* vb = &Vb[os & 1][0];
        if (os < 7) STAGE_V(&Vb[(os & 1) ^ 1][0], os + 1);

        const int jA = os * 64 + fq8;
        const int jB = jA + 32;

        u16x8 vhA, vhB;
        {
            float4 r0a = *(const float4*)(rt + jA), r0b = *(const float4*)(rt + jA + 4);
            float4 r1a = *(const float4*)(rt + 512 + jA), r1b = *(const float4*)(rt + 512 + jA + 4);
            float4 r2a = *(const float4*)(rt + 1024 + jA), r2b = *(const float4*)(rt + 1024 + jA + 4);
            float e0[8] = {r0a.x, r0a.y, r0a.z, r0a.w, r0b.x, r0b.y, r0b.z, r0b.w};
            float e1[8] = {r1a.x, r1a.y, r1a.z, r1a.w, r1b.x, r1b.y, r1b.z, r1b.w};
            float e2[8] = {r2a.x, r2a.y, r2a.z, r2a.w, r2b.x, r2b.y, r2b.z, r2b.w};
            #pragma unroll
            for (int q = 0; q < 8; ++q) {
                unsigned av = ((q < 4 ? aA.x : aA.y) >> (8 * (q & 3))) & 255u;
                float sb = (av == 1u) ? (lf0 + e0[q])
                         : (av == 2u) ? (lf1 + e1[q]) : (lf2 + e2[q]);
                float sv = fmaxf(sb, 0.f) + 0.2f * fminf(sb, 0.f);
                float p = (av != 0u) ? __expf(sv) : 0.f;
                rsum += p;
                vhA[q] = f2h(p);
            }
        }
        {
            float4 r0a = *(const float4*)(rt + jB), r0b = *(const float4*)(rt + jB + 4);
            float4 r1a = *(const float4*)(rt + 512 + jB), r1b = *(const float4*)(rt + 512 + jB + 4);
            float4 r2a = *(const float4*)(rt + 1024 + jB), r2b = *(const float4*)(rt + 1024 + jB + 4);
            float e0[8] = {r0a.x, r0a.y, r0a.z, r0a.w, r0b.x, r0b.y, r0b.z, r0b.w};
            float e1[8] = {r1a.x, r1a.y, r1a.z, r1a.w, r1b.x, r1b.y, r1b.z, r1b.w};
            float e2[8] = {r2a.x, r2a.y, r2a.z, r2a.w, r2b.x, r2b.y, r2b.z, r2b.w};
            #pragma unroll
            for (int q = 0; q < 8; ++q) {
                unsigned av = ((q < 4 ? aB.x : aB.y) >> (8 * (q & 3))) & 255u;
                float sb = (av == 1u) ? (lf0 + e0[q])
                         : (av == 2u) ? (lf1 + e1[q]) : (lf2 + e2[q]);
                float sv = fmaxf(sb, 0.f) + 0.2f * fminf(sb, 0.f);
                float p = (av != 0u) ? __expf(sv) : 0.f;
                rsum += p;
                vhB[q] = f2h(p);
            }
        }
        if (os < 7) {
            aA = *(const uint2*)(arow + (os + 1) * 64 + fq8);
            aB = *(const uint2*)(arow + (os + 1) * 64 + fq8 + 32);
        }

        half8 ahA = *(half8*)&vhA, ahB = *(half8*)&vhB;

        #pragma unroll
        for (int n = 0; n < 8; ++n) {
            half8 vA = *(half8*)(vb + (n * 2 + 0) * 512 + lane * 8);
            half8 vB = *(half8*)(vb + (n * 2 + 1) * 512 + lane * 8);
            acc[n] = __builtin_amdgcn_mfma_f32_16x16x32_f16(ahA, vA, acc[n], 0, 0, 0);
            acc[n] = __builtin_amdgcn_mfma_f32_16x16x32_f16(ahB, vB, acc[n], 0, 0, 0);
        }
        __syncthreads();
    }
#undef STAGE_V

    rsum += __shfl_xor(rsum, 16);
    rsum += __shfl_xor(rsum, 32);

    #pragma unroll
    for (int rr = 0; rr < 4; ++rr) {
        const int row = fq * 4 + rr;
        const float inv = 1.0f / __shfl(rsum, row);
        #pragma unroll
        for (int n = 0; n < 8; ++n) {
            out[(size_t)(b * 512 + i0 + row) * 1024 + h * 128 + n * 16 + fr] =
                fmaxf(acc[n][rr] * inv, 0.f);
        }
    }
}

// ---------------------------------------------------------------------------
extern "C" void kernel_launch(void* const* d_in, const int* in_sizes, int n_in,
                              void* d_out, int out_size, void* d_ws, size_t ws_size,
                              hipStream_t stream) {
    const float* x   = (const float*)d_in[0];
    const int*   adj = (const int*)d_in[1];
    const float* nm  = (const float*)d_in[2];
    const float* W   = (const float*)d_in[3];
    const float* a1  = (const float*)d_in[4];
    const float* a2  = (const float*)d_in[5];
    float* out = (float*)d_out;
    char* wsb = (char*)d_ws;

    unsigned short* Bf   = (unsigned short*)(wsb);
    float*          LR   = (float*)(wsb + 21495808);
    unsigned short* Vt   = (unsigned short*)(wsb + 23068672);
    unsigned char*  adjB = (unsigned char*)(wsb + 39845888);

    hipLaunchKernelGGL(prep_kernel, dim3(1616), dim3(256), 0, stream, adj, W, a1, a2, Bf, adjB);
    hipLaunchKernelGGL(mgemm, dim3(576), dim3(256), 0, stream, x, Bf, nm, Vt, LR);
    hipLaunchKernelGGL(attn_kernel, dim3(1024), dim3(256), 0, stream, Vt, LR, adjB, out);
}

// Round 24
// 97.416 us; speedup vs baseline: 1.5450x; 1.1125x over previous
//
#include <hip/hip_runtime.h>

typedef __attribute__((ext_vector_type(8))) _Float16 half8;
typedef __attribute__((ext_vector_type(8))) unsigned short u16x8;
typedef __attribute__((ext_vector_type(4))) unsigned short u16x4;
typedef __attribute__((ext_vector_type(4))) float f32x4;

#define NEGV (-1e30f)

// ---------------------------------------------------------------------------
// Workspace layout (bytes):
//  Bf  : [1152][1024] fp16 @ 0          (2,359,296)   packed B (single fp16)
//  LR  : [48][8192]  f32   @ 21495808   (1,572,864)
//  Vt  : [8][16][128][512] fp16 @ 23068672 (16,777,216)  written by mgemm
//  adjB: [16][512][512] u8 @ 39845888   (4,194,304)
//  total 44,040,192 B
// ---------------------------------------------------------------------------

__device__ __forceinline__ unsigned short f2h(float f) {
    union { _Float16 h; unsigned short u; } c;
    c.h = (_Float16)f;
    return c.u;
}
__device__ __forceinline__ float h2f(unsigned short u) {
    union { _Float16 h; unsigned short u; } c;
    c.u = u;
    return (float)c.h;
}

// ---------------------------------------------------------------------------
// Kernel 1: fused prep (adj->bytes + pack tr/wa/zero).  grid 1616. [verified]
// ---------------------------------------------------------------------------
__global__ __launch_bounds__(256) void prep_kernel(const int* __restrict__ adj,
                                                   const float* __restrict__ W,
                                                   const float* __restrict__ a1,
                                                   const float* __restrict__ a2,
                                                   unsigned short* __restrict__ Bf,
                                                   unsigned char* __restrict__ adjB) {
    __shared__ float tile[64 * 133];
    const int bid = blockIdx.x;
    const int tid = threadIdx.x;

    if (bid < 1024) {
        const int idx = bid * 256 + tid;
        const int4* s = (const int4*)(adj + (size_t)idx * 16);
        int4 v0 = s[0], v1 = s[1], v2 = s[2], v3 = s[3];
        union { unsigned char c[16]; int4 v; } o;
        o.c[0] = (unsigned char)v0.x; o.c[1] = (unsigned char)v0.y;
        o.c[2] = (unsigned char)v0.z; o.c[3] = (unsigned char)v0.w;
        o.c[4] = (unsigned char)v1.x; o.c[5] = (unsigned char)v1.y;
        o.c[6] = (unsigned char)v1.z; o.c[7] = (unsigned char)v1.w;
        o.c[8] = (unsigned char)v2.x; o.c[9] = (unsigned char)v2.y;
        o.c[10] = (unsigned char)v2.z; o.c[11] = (unsigned char)v2.w;
        o.c[12] = (unsigned char)v3.x; o.c[13] = (unsigned char)v3.y;
        o.c[14] = (unsigned char)v3.z; o.c[15] = (unsigned char)v3.w;
        *(int4*)(adjB + (size_t)idx * 16) = o.v;
    } else if (bid < 1152) {
        const int pb = bid - 1024;
        const int kt = pb & 15, h = pb >> 4;
        const int k0 = kt * 64;
        const float* wsrc = W + ((size_t)((h * 3 + 2) * 1024) + k0) * 128;

        #pragma unroll
        for (int rep = 0; rep < 8; ++rep) {
            int idx = rep * 256 + tid;
            int k = idx >> 5, dc = (idx & 31) * 4;
            float4 v = *(const float4*)(wsrc + (size_t)k * 128 + dc);
            tile[k * 133 + dc + 0] = v.x;
            tile[k * 133 + dc + 1] = v.y;
            tile[k * 133 + dc + 2] = v.z;
            tile[k * 133 + dc + 3] = v.w;
        }
        __syncthreads();
        #pragma unroll
        for (int rep = 0; rep < 4; ++rep) {
            int idx = rep * 256 + tid;
            int d = idx >> 3, kc = (idx & 7) * 8;
            u16x8 vh;
            #pragma unroll
            for (int q = 0; q < 8; ++q) vh[q] = f2h(tile[(kc + q) * 133 + d]);
            *(u16x8*)(Bf + (size_t)(h * 128 + d) * 1024 + k0 + kc) = vh;
        }
    } else if (bid < 1536) {
        const int pb = bid - 1152;
        const int kt = pb & 15, ht = pb >> 4;
        const int h = ht & 7, t = ht >> 3;
        const int k0 = kt * 64;
        const float* wsrc = W + ((size_t)((h * 3 + t) * 1024) + k0) * 128;

        #pragma unroll
        for (int rep = 0; rep < 8; ++rep) {
            int idx = rep * 256 + tid;
            int k = idx >> 5, dc = (idx & 31) * 4;
            float4 v = *(const float4*)(wsrc + (size_t)k * 128 + dc);
            tile[k * 133 + dc + 0] = v.x;
            tile[k * 133 + dc + 1] = v.y;
            tile[k * 133 + dc + 2] = v.z;
            tile[k * 133 + dc + 3] = v.w;
        }
        __syncthreads();
        if (tid < 128) {
            const int k = tid & 63, s = tid >> 6;
            const float* ar = (s ? a2 : a1) + (h * 3 + t) * 128;
            float acc = 0.f;
            #pragma unroll 4
            for (int d = 0; d < 128; ++d) acc += tile[k * 133 + d] * ar[d];
            Bf[(size_t)(1024 + s * 24 + t * 8 + h) * 1024 + k0 + k] = f2h(acc);
        }
    } else {
        const int n = 1072 + (bid - 1536);
        *(unsigned long long*)(Bf + (size_t)n * 1024 + tid * 4) = 0ull;
    }
}

// ---------------------------------------------------------------------------
// Kernel 2: fp16 MFMA GEMM — counted-vmcnt raw-barrier pipeline (T4):
//   per step: issue B gload_lds(t+1) [2 vmem], issue X(t+2) [4 vmem],
//   compute(t), convert X(t+1)->Ah(t+1), then
//   `s_waitcnt vmcnt(4) lgkmcnt(0); s_barrier` — B(t+1) drained, X(t+2)
//   stays in flight ACROSS the barrier. Issue order pinned by
//   sched_barrier(0). Manual 2x unroll -> all buffer/reg-set indices static.
// ---------------------------------------------------------------------------
__global__ __launch_bounds__(256, 3) void mgemm(const float* __restrict__ X,
                                                const unsigned short* __restrict__ Bf,
                                                const float* __restrict__ nm,
                                                unsigned short* __restrict__ Vt,
                                                float* __restrict__ LR) {
    __shared__ unsigned short Ah[2][128 * 32];
    __shared__ unsigned short Bfs[2][128 * 32];

    const int bid = blockIdx.x;                 // 0..575
    const int swz = (bid & 7) * 72 + (bid >> 3); // XCD-aware, bijective
    const int nt = swz % 9, mt = swz / 9;
    const int n0 = nt * 128, m0 = mt * 128;

    const int tid = threadIdx.x;
    const int lane = tid & 63, w = tid >> 6;
    const int wr = w >> 1, wc = w & 1;
    const int fr = lane & 15, fq = lane >> 4;

    f32x4 acc[4][4];
    #pragma unroll
    for (int m = 0; m < 4; ++m)
        #pragma unroll
        for (int n = 0; n < 4; ++n) acc[m][n] = (f32x4){0.f, 0.f, 0.f, 0.f};

    const int arow = tid >> 1, ahalf = tid & 1;
    const float* xs = X + (size_t)(m0 + arow) * 1024 + ahalf * 16;
    const int aoff = arow * 32 + ahalf * 16;

#define GLDB(kk, buf) do {                                                        \
        _Pragma("unroll")                                                          \
        for (int q_ = 0; q_ < 2; ++q_) {                                           \
            const int s_ = q_ * 256 + tid;                                         \
            const int brow_ = s_ >> 2, bkb_ = s_ & 3;                              \
            const unsigned short* g_ = Bf + (size_t)(n0 + brow_) * 1024 + (kk) + bkb_ * 8; \
            unsigned short* d_ = &Bfs[buf][(q_ * 256 + w * 64) * 8];               \
            __builtin_amdgcn_global_load_lds(                                      \
                (const __attribute__((address_space(1))) void*)g_,                 \
                (__attribute__((address_space(3))) void*)d_, 16, 0, 0);            \
        }                                                                          \
    } while (0)

#define CONVA(xa_, xb_, xc_, xd_, buf) do {                                       \
        float xf_[16] = {(xa_).x, (xa_).y, (xa_).z, (xa_).w,                       \
                         (xb_).x, (xb_).y, (xb_).z, (xb_).w,                       \
                         (xc_).x, (xc_).y, (xc_).z, (xc_).w,                       \
                         (xd_).x, (xd_).y, (xd_).z, (xd_).w};                      \
        u16x8 v0_, v1_;                                                            \
        _Pragma("unroll")                                                          \
        for (int i_ = 0; i_ < 8; ++i_) v0_[i_] = f2h(xf_[i_]);                     \
        _Pragma("unroll")                                                          \
        for (int i_ = 0; i_ < 8; ++i_) v1_[i_] = f2h(xf_[8 + i_]);                 \
        *(u16x8*)(&Ah[buf][aoff]) = v0_;                                           \
        *(u16x8*)(&Ah[buf][aoff + 8]) = v1_;                                       \
    } while (0)

#define COMPUTE(buf) do {                                                         \
        half8 am_[4], bn_[4];                                                      \
        _Pragma("unroll")                                                          \
        for (int m_ = 0; m_ < 4; ++m_)                                             \
            am_[m_] = *(half8*)(&Ah[buf][(wr * 64 + m_ * 16 + fr) * 32 + fq * 8]); \
        _Pragma("unroll")                                                          \
        for (int n_ = 0; n_ < 4; ++n_)                                             \
            bn_[n_] = *(half8*)(&Bfs[buf][(wc * 64 + n_ * 16 + fr) * 32 + fq * 8]);\
        _Pragma("unroll")                                                          \
        for (int m_ = 0; m_ < 4; ++m_)                                             \
            _Pragma("unroll")                                                      \
            for (int n_ = 0; n_ < 4; ++n_)                                         \
                acc[m_][n_] = __builtin_amdgcn_mfma_f32_16x16x32_f16(am_[m_], bn_[n_], acc[m_][n_], 0, 0, 0); \
    } while (0)

#define PIPE_BAR4() asm volatile("s_waitcnt vmcnt(4) lgkmcnt(0)\n\ts_barrier" ::: "memory")
#define PIPE_BAR0() asm volatile("s_waitcnt vmcnt(0) lgkmcnt(0)\n\ts_barrier" ::: "memory")

    float4 x0a, x0b, x0c, x0d, x1a, x1b, x1c, x1d;

    // ---- prologue: X(0) loads, B(0) gloads, convert X(0)->Ah[0], X(1) loads
    x0a = *(const float4*)(xs);
    x0b = *(const float4*)(xs + 4);
    x0c = *(const float4*)(xs + 8);
    x0d = *(const float4*)(xs + 12);
    __builtin_amdgcn_sched_barrier(0);
    GLDB(0, 0);
    __builtin_amdgcn_sched_barrier(0);
    CONVA(x0a, x0b, x0c, x0d, 0);       // waits X(0); B(0) stays in flight
    x1a = *(const float4*)(xs + 32);
    x1b = *(const float4*)(xs + 36);
    x1c = *(const float4*)(xs + 40);
    x1d = *(const float4*)(xs + 44);
    PIPE_BAR4();                        // drains B(0); X(1) crosses barrier

    // ---- main loop: steps t=0..29 as 15 double-steps
    for (int kk = 0; kk < 928; kk += 64) {
        // even step t = kk/32 : cur=0
        GLDB(kk + 32, 1);
        __builtin_amdgcn_sched_barrier(0);
        x0a = *(const float4*)(xs + kk + 64);
        x0b = *(const float4*)(xs + kk + 68);
        x0c = *(const float4*)(xs + kk + 72);
        x0d = *(const float4*)(xs + kk + 76);
        __builtin_amdgcn_sched_barrier(0);
        COMPUTE(0);
        CONVA(x1a, x1b, x1c, x1d, 1);   // X(t+1) -> Ah[1]
        PIPE_BAR4();                    // drains B(t+1); X(t+2) in flight

        // odd step t+1 : cur=1
        GLDB(kk + 64, 0);
        __builtin_amdgcn_sched_barrier(0);
        x1a = *(const float4*)(xs + kk + 96);
        x1b = *(const float4*)(xs + kk + 100);
        x1c = *(const float4*)(xs + kk + 104);
        x1d = *(const float4*)(xs + kk + 108);
        __builtin_amdgcn_sched_barrier(0);
        COMPUTE(1);
        CONVA(x0a, x0b, x0c, x0d, 0);   // X(t+2) -> Ah[0]
        PIPE_BAR4();
    }

    // ---- tail: t=30 (cur=0), t=31 (cur=1)
    GLDB(992, 1);
    __builtin_amdgcn_sched_barrier(0);
    COMPUTE(0);                          // col 960
    CONVA(x1a, x1b, x1c, x1d, 1);        // X col 992 -> Ah[1]
    PIPE_BAR0();                         // drain everything (last stage)
    COMPUTE(1);                          // col 992

#undef GLDB
#undef CONVA
#undef COMPUTE
#undef PIPE_BAR4
#undef PIPE_BAR0

    // ---- epilogue: C/D layout col=lane&15, row=(lane>>4)*4+reg
    if (nt < 8) {
        const int b_ = (mt * 128) >> 9;
        const int jb0 = (mt & 3) * 128;
        unsigned short* vtw = Vt + (size_t)(nt * 16 + b_) * 128 * 512;
        #pragma unroll
        for (int m = 0; m < 4; ++m) {
            const int jb = jb0 + wr * 64 + m * 16 + fq * 4;
            float mk[4];
            #pragma unroll
            for (int r = 0; r < 4; ++r)
                mk[r] = nm[m0 + wr * 64 + m * 16 + fq * 4 + r];
            #pragma unroll
            for (int n = 0; n < 4; ++n) {
                const int d = wc * 64 + n * 16 + fr;
                u16x4 pk;
                #pragma unroll
                for (int r = 0; r < 4; ++r) pk[r] = f2h(acc[m][n][r] * mk[r]);
                *(u16x4*)(vtw + (size_t)d * 512 + jb) = pk;
            }
        }
    } else {
        #pragma unroll
        for (int m = 0; m < 4; ++m) {
            #pragma unroll
            for (int r = 0; r < 4; ++r) {
                const int R = m0 + wr * 64 + m * 16 + fq * 4 + r;
                #pragma unroll
                for (int n = 0; n < 4; ++n) {
                    const int c = wc * 64 + n * 16 + fr;
                    if (c < 48) LR[(size_t)c * 8192 + R] = acc[m][n][r];
                }
            }
        }
    }
}

// ---------------------------------------------------------------------------
// Kernel 4: fused attn — r22-exact (verified): P single fp16, 16 MFMA/step.
// ---------------------------------------------------------------------------
__global__ __launch_bounds__(256, 4) void attn_kernel(const unsigned short* __restrict__ Vt,
                                                      const float* __restrict__ LR,
                                                      const unsigned char* __restrict__ adjB,
                                                      float* __restrict__ out) {
    __shared__ __align__(16) unsigned short Vb[2][16 * 512];
    __shared__ __align__(16) float rt[3 * 512];

    const int bid = blockIdx.x;
    const int itg = bid >> 7, hb = bid & 127, h = hb >> 4, b = hb & 15;
    const int tid = threadIdx.x, w = tid >> 6, lane = tid & 63;
    const int fr = lane & 15, fq = lane >> 4;
    const int i0 = (itg * 4 + w) * 16;
    const int fq8 = fq * 8;

    for (int idx = tid; idx < 1536; idx += 256) {
        int t = idx >> 9, j = idx & 511;
        rt[idx] = LR[(size_t)(24 + t * 8 + h) * 8192 + b * 512 + j];
    }
    const float lf0 = LR[(size_t)(h) * 8192 + b * 512 + i0 + fr];
    const float lf1 = LR[(size_t)(8 + h) * 8192 + b * 512 + i0 + fr];
    const float lf2 = LR[(size_t)(16 + h) * 8192 + b * 512 + i0 + fr];
    const unsigned char* arow = adjB + (size_t)(b * 512 + i0 + fr) * 512;
    const unsigned short* vt = Vt + (size_t)(h * 16 + b) * 128 * 512;

#define STAGE_V(bufp, os_) do {                                                   \
        _Pragma("unroll")                                                          \
        for (int q_ = 0; q_ < 4; ++q_) {                                           \
            const int nh_ = q_ * 4 + w;                                            \
            const unsigned short* src_ = vt + (size_t)((nh_ >> 1) * 16 + fr) * 512 \
                                          + (os_) * 64 + (nh_ & 1) * 32 + fq8;     \
            unsigned short* dst_ = (bufp) + nh_ * 512;                             \
            __builtin_amdgcn_global_load_lds(                                      \
                (const __attribute__((address_space(1))) void*)src_,               \
                (__attribute__((address_space(3))) void*)dst_, 16, 0, 0);          \
        }                                                                          \
    } while (0)

    STAGE_V(&Vb[0][0], 0);
    uint2 aA = *(const uint2*)(arow + fq8);
    uint2 aB = *(const uint2*)(arow + fq8 + 32);

    f32x4 acc[8];
    #pragma unroll
    for (int n = 0; n < 8; ++n) acc[n] = (f32x4){0.f, 0.f, 0.f, 0.f};
    float rsum = 0.f;

    __syncthreads();

    #pragma unroll 1
    for (int os = 0; os < 8; ++os) {
        unsigned short* vb = &Vb[os & 1][0];
        if (os < 7) STAGE_V(&Vb[(os & 1) ^ 1][0], os + 1);

        const int jA = os * 64 + fq8;
        const int jB = jA + 32;

        u16x8 vhA, vhB;
        {
            float4 r0a = *(const float4*)(rt + jA), r0b = *(const float4*)(rt + jA + 4);
            float4 r1a = *(const float4*)(rt + 512 + jA), r1b = *(const float4*)(rt + 512 + jA + 4);
            float4 r2a = *(const float4*)(rt + 1024 + jA), r2b = *(const float4*)(rt + 1024 + jA + 4);
            float e0[8] = {r0a.x, r0a.y, r0a.z, r0a.w, r0b.x, r0b.y, r0b.z, r0b.w};
            float e1[8] = {r1a.x, r1a.y, r1a.z, r1a.w, r1b.x, r1b.y, r1b.z, r1b.w};
            float e2[8] = {r2a.x, r2a.y, r2a.z, r2a.w, r2b.x, r2b.y, r2b.z, r2b.w};
            #pragma unroll
            for (int q = 0; q < 8; ++q) {
                unsigned av = ((q < 4 ? aA.x : aA.y) >> (8 * (q & 3))) & 255u;
                float sb = (av == 1u) ? (lf0 + e0[q])
                         : (av == 2u) ? (lf1 + e1[q]) : (lf2 + e2[q]);
                float sv = fmaxf(sb, 0.f) + 0.2f * fminf(sb, 0.f);
                float p = (av != 0u) ? __expf(sv) : 0.f;
                rsum += p;
                vhA[q] = f2h(p);
            }
        }
        {
            float4 r0a = *(const float4*)(rt + jB), r0b = *(const float4*)(rt + jB + 4);
            float4 r1a = *(const float4*)(rt + 512 + jB), r1b = *(const float4*)(rt + 512 + jB + 4);
            float4 r2a = *(const float4*)(rt + 1024 + jB), r2b = *(const float4*)(rt + 1024 + jB + 4);
            float e0[8] = {r0a.x, r0a.y, r0a.z, r0a.w, r0b.x, r0b.y, r0b.z, r0b.w};
            float e1[8] = {r1a.x, r1a.y, r1a.z, r1a.w, r1b.x, r1b.y, r1b.z, r1b.w};
            float e2[8] = {r2a.x, r2a.y, r2a.z, r2a.w, r2b.x, r2b.y, r2b.z, r2b.w};
            #pragma unroll
            for (int q = 0; q < 8; ++q) {
                unsigned av = ((q < 4 ? aB.x : aB.y) >> (8 * (q & 3))) & 255u;
                float sb = (av == 1u) ? (lf0 + e0[q])
                         : (av == 2u) ? (lf1 + e1[q]) : (lf2 + e2[q]);
                float sv = fmaxf(sb, 0.f) + 0.2f * fminf(sb, 0.f);
                float p = (av != 0u) ? __expf(sv) : 0.f;
                rsum += p;
                vhB[q] = f2h(p);
            }
        }
        if (os < 7) {
            aA = *(const uint2*)(arow + (os + 1) * 64 + fq8);
            aB = *(const uint2*)(arow + (os + 1) * 64 + fq8 + 32);
        }

        half8 ahA = *(half8*)&vhA, ahB = *(half8*)&vhB;

        #pragma unroll
        for (int n = 0; n < 8; ++n) {
            half8 vA = *(half8*)(vb + (n * 2 + 0) * 512 + lane * 8);
            half8 vB = *(half8*)(vb + (n * 2 + 1) * 512 + lane * 8);
            acc[n] = __builtin_amdgcn_mfma_f32_16x16x32_f16(ahA, vA, acc[n], 0, 0, 0);
            acc[n] = __builtin_amdgcn_mfma_f32_16x16x32_f16(ahB, vB, acc[n], 0, 0, 0);
        }
        __syncthreads();
    }
#undef STAGE_V

    rsum += __shfl_xor(rsum, 16);
    rsum += __shfl_xor(rsum, 32);

    #pragma unroll
    for (int rr = 0; rr < 4; ++rr) {
        const int row = fq * 4 + rr;
        const float inv = 1.0f / __shfl(rsum, row);
        #pragma unroll
        for (int n = 0; n < 8; ++n) {
            out[(size_t)(b * 512 + i0 + row) * 1024 + h * 128 + n * 16 + fr] =
                fmaxf(acc[n][rr] * inv, 0.f);
        }
    }
}

// ---------------------------------------------------------------------------
extern "C" void kernel_launch(void* const* d_in, const int* in_sizes, int n_in,
                              void* d_out, int out_size, void* d_ws, size_t ws_size,
                              hipStream_t stream) {
    const float* x   = (const float*)d_in[0];
    const int*   adj = (const int*)d_in[1];
    const float* nm  = (const float*)d_in[2];
    const float* W   = (const float*)d_in[3];
    const float* a1  = (const float*)d_in[4];
    const float* a2  = (const float*)d_in[5];
    float* out = (float*)d_out;
    char* wsb = (char*)d_ws;

    unsigned short* Bf   = (unsigned short*)(wsb);
    float*          LR   = (float*)(wsb + 21495808);
    unsigned short* Vt   = (unsigned short*)(wsb + 23068672);
    unsigned char*  adjB = (unsigned char*)(wsb + 39845888);

    hipLaunchKernelGGL(prep_kernel, dim3(1616), dim3(256), 0, stream, adj, W, a1, a2, Bf, adjB);
    hipLaunchKernelGGL(mgemm, dim3(576), dim3(256), 0, stream, x, Bf, nm, Vt, LR);
    hipLaunchKernelGGL(attn_kernel, dim3(1024), dim3(256), 0, stream, Vt, LR, adjB, out);
}